// Round 11
// baseline (179.450 us; speedup 1.0000x reference)
//
#include <hip/hip_runtime.h>
#include <math.h>

#define BD 8
#define DD 1024
#define EE 256
#define HH 8
#define HDD 32
#define NBITS 11

typedef __attribute__((ext_vector_type(8))) short short8;
typedef __attribute__((ext_vector_type(4))) float f4;

__device__ __forceinline__ ushort f2bf(float f) {
  unsigned u = __float_as_uint(f);
  u += 0x7fffu + ((u >> 16) & 1u);
  return (ushort)(u >> 16);
}
__device__ __forceinline__ float bf2f(ushort u) {
  return __uint_as_float(((unsigned)u) << 16);
}
__device__ __forceinline__ void async_copy16(ushort* lds, const ushort* g) {
  __builtin_amdgcn_global_load_lds((const __attribute__((address_space(1))) void*)g,
                                   (__attribute__((address_space(3))) void*)lds, 16, 0, 0);
}

// ---------------- prologue: qscale (blocks 0-7) + weight bf16 conversion (blocks 8+) ----------------
// wbf layout: qw[65536] kw[65536] vw[65536] w1[131072] w2[131072] cw1[65536]
__global__ __launch_bounds__(256) void k_pre(const float* __restrict__ x,
                                             const float* __restrict__ film_alpha,
                                             const float* __restrict__ film_a,
                                             float* __restrict__ qscale,
                                             const float* __restrict__ qw,
                                             const float* __restrict__ kw,
                                             const float* __restrict__ vw,
                                             const float* __restrict__ w1,
                                             const float* __restrict__ w2,
                                             const float* __restrict__ cw1,
                                             ushort* __restrict__ o) {
  if (blockIdx.x < 8) {
    __shared__ float red[256];
    int b = blockIdx.x, t = threadIdx.x;
    float s = 0.f;
    #pragma unroll
    for (int i = 0; i < 4; i++) s += x[b * DD + t + i * 256];
    red[t] = s; __syncthreads();
    for (int off = 128; off > 0; off >>= 1) {
      if (t < off) red[t] += red[t + off];
      __syncthreads();
    }
    float total = red[0];
    float ta = tanhf(film_alpha[0]);
    float fa = film_a[0];
    #pragma unroll
    for (int i = 0; i < 4; i++) {
      int d = t + i * 256;
      float xn = (total - x[b * DD + d]) / 1023.0f;
      float qs = 1.0f + ta * tanhf(fa * xn);
      qs = fminf(fmaxf(qs, 0.7f), 1.3f);
      qscale[b * DD + d] = qs;
    }
  } else {
    int i = (int)(blockIdx.x - 8) * 256 + threadIdx.x;
    float v;
    if (i < 65536) v = qw[i];
    else if (i < 131072) v = kw[i - 65536];
    else if (i < 196608) v = vw[i - 131072];
    else if (i < 327680) v = w1[i - 196608];
    else if (i < 458752) v = w2[i - 327680];
    else v = cw1[i - 458752];
    o[i] = f2bf(v);
  }
}

// ---------------- kv/h init with inline pos: kv_bf=bf16(x*vw+vb+pos); h=pos; h_bf=bf16(pos) ----------------
__global__ __launch_bounds__(256) void k_kvh2(const float* __restrict__ x,
                                              const float* __restrict__ value_w,
                                              const float* __restrict__ value_b,
                                              const float* __restrict__ fe,
                                              const float* __restrict__ binary_w,
                                              ushort* __restrict__ kv_bf,
                                              float* __restrict__ h,
                                              ushort* __restrict__ h_bf) {
  int idx = blockIdx.x * 256 + threadIdx.x;   // over B*D*E = 2M
  int e = idx & (EE - 1);
  int d = (idx >> 8) & (DD - 1);
  int b = idx >> 18;
  float p = fe[d * EE + e];
  int code = d + 1;
  #pragma unroll
  for (int bit = 0; bit < NBITS; bit++) {
    float cb = (float)((code >> (NBITS - 1 - bit)) & 1) - 0.5f;
    p += cb * binary_w[e * NBITS + bit];
  }
  kv_bf[idx] = f2bf(x[b * DD + d] * value_w[e] + value_b[e] + p);
  h[idx] = p;
  h_bf[idx] = f2bf(p);
}

// ---------------- MFMA GEMM, double-buffered: C[M,N] = A[M,K] @ W[N,K]^T ----------------
// 64x64 tile, BK=64, 4 waves (2x2), wave tile 32x32; 2-phase LDS prefetch pipeline.
// EPI 0: KV proj -> col<256: K bf16 [B,H,D,32]; col>=256: V bf16 [B,H,32,D] (transposed)
// EPI 1: GELU    -> bf16 [M,N], v = gelu(acc + aux1[col])
// EPI 2: RES     -> hb32[row,col] += aux2[col]*(acc+aux1[col]) (fp32), C = bf16(new hb)
template <int EPI, int KT>
__global__ __launch_bounds__(256) void mgemm_k(const ushort* __restrict__ A,
                                               const ushort* __restrict__ Bw,
                                               ushort* __restrict__ C,
                                               ushort* __restrict__ C2,
                                               int N,
                                               const float* __restrict__ aux1,
                                               const float* __restrict__ aux2,
                                               float* __restrict__ hb32) {
  __shared__ ushort As[2][64 * 64];
  __shared__ ushort Bs[2][64 * 64];
  int tid = threadIdx.x;
  int w = tid >> 6, lane = tid & 63;
  int c = lane & 15, g = lane >> 4;
  int wr = w >> 1, wc = w & 1;
  int lr = lane >> 3, lsl = lane & 7;

  const ushort* Ab = A + (size_t)(blockIdx.y * 64) * KT;
  const ushort* Bb = Bw + (size_t)(blockIdx.x * 64) * KT;

  f4 acc[2][2] = {};
  const int NT = KT / 64;

#define STAGE(buf, kt) do {                                                             \
    _Pragma("unroll")                                                                   \
    for (int j = 0; j < 2; j++) {                                                       \
      int rl = j * 32 + w * 8 + lr;                                                     \
      int slot = lsl ^ (rl & 7);                                                        \
      async_copy16(&As[buf][(j * 32 + w * 8) * 64], Ab + (size_t)rl * KT + (kt) * 64 + slot * 8); \
      async_copy16(&Bs[buf][(j * 32 + w * 8) * 64], Bb + (size_t)rl * KT + (kt) * 64 + slot * 8); \
    } } while (0)

  STAGE(0, 0);
  __syncthreads();   // drain vmcnt(0): tile 0 ready

  #pragma unroll
  for (int kt = 0; kt < NT; kt++) {
    int cur = kt & 1;
    if (kt + 1 < NT) STAGE(cur ^ 1, kt + 1);   // prefetch next tile; latency hides under compute
    #pragma unroll
    for (int ks2 = 0; ks2 < 2; ks2++) {
      short8 af[2], bf_[2];
      #pragma unroll
      for (int mi = 0; mi < 2; mi++) {
        int rowl = wr * 32 + mi * 16 + c;
        int slot = (ks2 * 4 + g) ^ (rowl & 7);
        af[mi] = *(const short8*)&As[cur][rowl * 64 + slot * 8];
      }
      #pragma unroll
      for (int ni = 0; ni < 2; ni++) {
        int rowl = wc * 32 + ni * 16 + c;
        int slot = (ks2 * 4 + g) ^ (rowl & 7);
        bf_[ni] = *(const short8*)&Bs[cur][rowl * 64 + slot * 8];
      }
      #pragma unroll
      for (int mi = 0; mi < 2; mi++)
        #pragma unroll
        for (int ni = 0; ni < 2; ni++)
          acc[mi][ni] = __builtin_amdgcn_mfma_f32_16x16x32_bf16(af[mi], bf_[ni], acc[mi][ni], 0, 0, 0);
    }
    __syncthreads();   // next tile loaded AND everyone done reading buf[cur]
  }
#undef STAGE

  // epilogue: D element (mi,ni,r) -> row = m0+mi*16+4g+r, col = n0+ni*16+c
  int m0 = blockIdx.y * 64 + wr * 32;
  int n0 = blockIdx.x * 64 + wc * 32;
  #pragma unroll
  for (int mi = 0; mi < 2; mi++) {
    #pragma unroll
    for (int ni = 0; ni < 2; ni++) {
      #pragma unroll
      for (int r = 0; r < 4; r++) {
        int row = m0 + mi * 16 + 4 * g + r;
        int col = n0 + ni * 16 + c;
        float v = acc[mi][ni][r];
        if (EPI == 0) {
          int bI = row >> 10, dI = row & 1023;
          if (col < 256) {
            int hI = col >> 5, eI = col & 31;
            C[(((size_t)(bI * HH + hI)) * DD + dI) * HDD + eI] = f2bf(v);
          } else {
            int ch = col - 256;
            int hI = ch >> 5, eI = ch & 31;
            C2[(((size_t)(bI * HH + hI)) * HDD + eI) * DD + dI] = f2bf(v);
          }
        } else if (EPI == 1) {
          v += aux1[col];
          float gl = 0.5f * v * (1.0f + erff(v * 0.70710678118654752f));
          C[(size_t)row * N + col] = f2bf(gl);
        } else if (EPI == 2) {
          v += aux1[col];
          size_t idx = (size_t)row * EE + col;
          float nh = hb32[idx] + aux2[col] * v;
          hb32[idx] = nh;
          C[idx] = f2bf(nh);
        }
      }
    }
  }
}

// ---------------- MFMA flash attention v6: fused Q-proj + XCD swizzle + static softmax + window cut ----------------
// hbf: bf16 [B*D, E] residual stream; qwb: bf16 qw [E,E]; Kbf: bf16 [B,H,D,32]; Vtb: bf16 [B,H,32,D].
// grid 1024 (swizzled); 4 waves, each owns 16 queries of a 64-q diag block.
__global__ __launch_bounds__(256) void attn6_k(const ushort* __restrict__ hbf,
                                               const ushort* __restrict__ qwb,
                                               const float* __restrict__ qscale,
                                               const ushort* __restrict__ Kbf,
                                               const ushort* __restrict__ Vtb,
                                               const float* __restrict__ gamma,
                                               const float* __restrict__ strength_p,
                                               float* __restrict__ h) {
  __shared__ __align__(16) ushort Pl[4][16][88];   // per-wave tile: Q staging, then P tiles
  int tid = threadIdx.x;
  int w = tid >> 6, lane = tid & 63;
  int c = lane & 15, g = lane >> 4;
  // XCD-aware bijective swizzle: all 16 q-blocks of a (b,h) share an XCD
  int lid = (blockIdx.x & 7) * 128 + (blockIdx.x >> 3);
  int bh = lid >> 4;
  int diag = lid & 15;
  int b = bh >> 3, hh = bh & 7;
  int q0w = diag * 64 + w * 16;
  int qg = q0w + c;
  float ss = fmaxf(strength_p[0], 0.f) * exp2f(-(float)hh / 8.0f);
  const float L2E = 1.4426950408889634f;

  // ---- fused Q projection: Q[16q x 32e] per wave, K=256 ----
  f4 qa0 = {0.f, 0.f, 0.f, 0.f}, qa1 = {0.f, 0.f, 0.f, 0.f};
  {
    const ushort* Abp = hbf + ((size_t)(b * DD + q0w + c)) * EE + 8 * g;
    const ushort* Bb0 = qwb + ((size_t)(hh * HDD + c)) * EE + 8 * g;
    const ushort* Bb1 = Bb0 + (size_t)16 * EE;
    #pragma unroll
    for (int kk = 0; kk < 8; kk++) {
      short8 a  = *(const short8*)(Abp + kk * 32);
      short8 b0 = *(const short8*)(Bb0 + kk * 32);
      short8 b1 = *(const short8*)(Bb1 + kk * 32);
      qa0 = __builtin_amdgcn_mfma_f32_16x16x32_bf16(a, b0, qa0, 0, 0, 0);
      qa1 = __builtin_amdgcn_mfma_f32_16x16x32_bf16(a, b1, qa1, 0, 0, 0);
    }
  }
  // scale by qscale[row]/sqrt(32), stage via LDS to reach B-operand fragment layout
  {
    const float4 qsv = *(const float4*)&qscale[b * DD + q0w + 4 * g];
    float qs[4] = {qsv.x, qsv.y, qsv.z, qsv.w};
    #pragma unroll
    for (int r = 0; r < 4; r++) {
      float sc = qs[r] * 0.17677669529663687f;
      Pl[w][4 * g + r][c]      = f2bf(qa0[r] * sc);
      Pl[w][4 * g + r][16 + c] = f2bf(qa1[r] * sc);
    }
  }
  // wave-internal LDS write->read is in-order: no barrier needed
  short8 qf = *(const short8*)&Pl[w][c][8 * g];   // lane holds Q[q0w+c][8g..8g+7]

  f4 oacc0 = {0.f, 0.f, 0.f, 0.f};
  f4 oacc1 = {0.f, 0.f, 0.f, 0.f};
  float lpart = 0.f;

  const ushort* Kb0 = Kbf + (((size_t)bh * DD + c) << 5) + (g << 3);
  const ushort* Vb0 = Vtb + ((size_t)(bh * HDD + c)) * DD + (g << 3);

  for (int kk = 0; kk < 16; kk++) {
    int ks = (diag + kk) & 15;
    if (kk) {
      // window cut: relative contribution bound < e^-14 -> negligible
      int dmin = (ks > diag) ? (ks * 64 - (q0w - w * 16 + 15) - w * 16) : 0;
      dmin = (ks > diag) ? (ks * 64 - (diag * 64 + 63)) : (diag * 64 - (ks * 64 + 63));
      if (ss * (float)dmin > 14.0f) continue;
    }
    // ---- QK^T (swapped): 4 tiles of 16 keys, S^T[k][q], full K=32 contraction ----
    f4 sa[4];
    #pragma unroll
    for (int t = 0; t < 4; t++) {
      short8 kf = *(const short8*)(Kb0 + (((size_t)(ks * 64 + t * 16)) << 5));
      f4 z = {0.f, 0.f, 0.f, 0.f};
      sa[t] = __builtin_amdgcn_mfma_f32_16x16x32_bf16(kf, qf, z, 0, 0, 0);
    }
    // ---- bias (lane owns query col c; key = ks*64 + t*16 + 4g + r) ----
    float s[16];
    if (kk == 0) {
      #pragma unroll
      for (int t = 0; t < 4; t++) {
        #pragma unroll
        for (int r = 0; r < 4; r++) {
          int k = ks * 64 + t * 16 + 4 * g + r;
          float ad = fabsf((float)(qg - k));
          s[t * 4 + r] = (k == qg) ? -1e30f : fmaf(-ss, ad, sa[t][r]);
        }
      }
    } else {
      float sgn = (ks > diag) ? -ss : ss;   // bias = sgn*(k - qg), always <= 0
      int kb = ks * 64 + 4 * g - qg;
      #pragma unroll
      for (int t = 0; t < 4; t++) {
        #pragma unroll
        for (int r = 0; r < 4; r++) {
          float dk = (float)(kb + t * 16 + r);
          s[t * 4 + r] = fmaf(sgn, dk, sa[t][r]);
        }
      }
    }
    // ---- static-reference exp (scores provably << 1) + partial sum + truncated bf16 pack ----
    #pragma unroll
    for (int i = 0; i < 16; i++) {
      float p = exp2f(s[i] * L2E);
      s[i] = p;
      lpart += p;
    }
    #pragma unroll
    for (int t = 0; t < 4; t++) {
      uint2 u;
      u.x = __builtin_amdgcn_perm(__float_as_uint(s[t * 4 + 1]), __float_as_uint(s[t * 4 + 0]), 0x07060302u);
      u.y = __builtin_amdgcn_perm(__float_as_uint(s[t * 4 + 3]), __float_as_uint(s[t * 4 + 2]), 0x07060302u);
      *(uint2*)&Pl[w][c][t * 16 + 4 * g] = u;
    }
    // ---- PV: O[q][e] += P[q][k] V[k][e], two K=32 halves, two e-tiles ----
    #pragma unroll
    for (int hb2 = 0; hb2 < 2; hb2++) {
      short8 pa = *(const short8*)&Pl[w][c][hb2 * 32 + 8 * g];
      short8 v0 = *(const short8*)(Vb0 + ks * 64 + hb2 * 32);
      short8 v1 = *(const short8*)(Vb0 + (size_t)16 * DD + ks * 64 + hb2 * 32);
      oacc0 = __builtin_amdgcn_mfma_f32_16x16x32_bf16(pa, v0, oacc0, 0, 0, 0);
      oacc1 = __builtin_amdgcn_mfma_f32_16x16x32_bf16(pa, v1, oacc1, 0, 0, 0);
    }
  }

  // ---- l reduce across the 4 lanes sharing query c ----
  lpart += __shfl_xor(lpart, 16);
  lpart += __shfl_xor(lpart, 32);
  float linv = 1.0f / lpart;

  // ---- epilogue: h += gamma * O / l ----
  #pragma unroll
  for (int r = 0; r < 4; r++) {
    float li = __shfl(linv, 4 * g + r);
    int q = q0w + 4 * g + r;
    size_t base = ((size_t)(b * DD + q)) * EE + hh * HDD;
    int e0 = c, e1 = 16 + c;
    h[base + e0] += gamma[hh * HDD + e0] * oacc0[r] * li;
    h[base + e1] += gamma[hh * HDD + e1] * oacc1[r] * li;
  }
}

// ---------------- LayerNorm: one wave per row, float4 + shuffle reduce, no barriers ----------------
__global__ __launch_bounds__(256) void ln_k(const float* __restrict__ hin,
                                            const float* __restrict__ w,
                                            const float* __restrict__ bb,
                                            ushort* __restrict__ y) {
  int row = blockIdx.x * 4 + (threadIdx.x >> 6);
  int lane = threadIdx.x & 63;
  const float4 v = *(const float4*)&hin[(size_t)row * EE + lane * 4];
  float s  = v.x + v.y + v.z + v.w;
  float s2 = v.x * v.x + v.y * v.y + v.z * v.z + v.w * v.w;
  #pragma unroll
  for (int off = 32; off; off >>= 1) {
    s  += __shfl_xor(s, off);
    s2 += __shfl_xor(s2, off);
  }
  float mean = s * (1.0f / EE);
  float var = s2 * (1.0f / EE) - mean * mean;
  float rs = rsqrtf(var + 1e-5f);
  const float4 wv = *(const float4*)&w[lane * 4];
  const float4 bv = *(const float4*)&bb[lane * 4];
  ushort4 o;
  o.x = f2bf((v.x - mean) * rs * wv.x + bv.x);
  o.y = f2bf((v.y - mean) * rs * wv.y + bv.y);
  o.z = f2bf((v.z - mean) * rs * wv.z + bv.z);
  o.w = f2bf((v.w - mean) * rs * wv.w + bv.w);
  *(ushort4*)&y[(size_t)row * EE + lane * 4] = o;
}

// ---------------- final projection to scalar per row ----------------
__global__ __launch_bounds__(256) void out_k(const ushort* __restrict__ t_,
                                             const float* __restrict__ w2,
                                             const float* __restrict__ b2,
                                             float* __restrict__ out) {
  int w = threadIdx.x >> 6, lane = threadIdx.x & 63;
  int r = blockIdx.x * 4 + w;
  float s = 0.f;
  #pragma unroll
  for (int i = 0; i < 4; i++) s += bf2f(t_[(size_t)r * EE + lane + i * 64]) * w2[lane + i * 64];
  #pragma unroll
  for (int off = 32; off; off >>= 1) s += __shfl_xor(s, off);
  if (lane == 0) out[r] = s + b2[0];
}

extern "C" void kernel_launch(void* const* d_in, const int* in_sizes, int n_in,
                              void* d_out, int out_size, void* d_ws, size_t ws_size,
                              hipStream_t stream) {
  const float* x            = (const float*)d_in[0];
  const float* value_w      = (const float*)d_in[1];
  const float* value_b      = (const float*)d_in[2];
  const float* feature_embed= (const float*)d_in[3];
  const float* binary_w     = (const float*)d_in[4];
  const float* qw           = (const float*)d_in[5];
  const float* kw           = (const float*)d_in[6];
  const float* vw           = (const float*)d_in[7];
  const float* film_alpha   = (const float*)d_in[8];
  const float* film_a       = (const float*)d_in[9];
  const float* ln1_w        = (const float*)d_in[10];
  const float* ln1_b        = (const float*)d_in[11];
  const float* ffn_w1       = (const float*)d_in[12];
  const float* ffn_b1       = (const float*)d_in[13];
  const float* ffn_w2       = (const float*)d_in[14];
  const float* ffn_b2       = (const float*)d_in[15];
  const float* gamma_attn   = (const float*)d_in[16];
  const float* gamma_ffn    = (const float*)d_in[17];
  const float* corr_ln_w    = (const float*)d_in[18];
  const float* corr_ln_b    = (const float*)d_in[19];
  const float* corr_w1      = (const float*)d_in[20];
  const float* corr_b1      = (const float*)d_in[21];
  const float* corr_w2      = (const float*)d_in[22];
  const float* corr_b2      = (const float*)d_in[23];
  const float* alibi_strength=(const float*)d_in[24];

  const size_t ME = (size_t)BD * DD * EE;   // 2M
  float* ws = (float*)d_ws;
  float* qscale = ws;                       // 8192 f
  float* hb     = qscale + BD * DD;         // 2M f
  ushort* kv_bf = (ushort*)(hb + ME);       // 2M us
  ushort* hb_bf = kv_bf + ME;               // 2M us
  ushort* yb_bf = hb_bf + ME;               // 2M us
  ushort* tb_bf = yb_bf + ME;               // 4M us
  ushort* Kbf   = tb_bf + 2 * ME;           // 2M us
  ushort* Vtb   = Kbf + ME;                 // 2M us
  ushort* wbf   = Vtb + ME;                 // 524288 us
  ushort* qwb   = wbf;
  ushort* kwb   = wbf + 65536;              // kw rows 0-255, vw rows 256-511 (contiguous)
  ushort* w1b   = wbf + 196608;
  ushort* w2b   = wbf + 327680;
  ushort* cw1b  = wbf + 458752;

  const int M = BD * DD;   // 8192

  k_pre<<<8 + 2048, 256, 0, stream>>>(x, film_alpha, film_a, qscale,
                                      qw, kw, vw, ffn_w1, ffn_w2, corr_w1, wbf);
  k_kvh2<<<(BD * DD * EE) / 256, 256, 0, stream>>>(x, value_w, value_b, feature_embed, binary_w,
                                                   kv_bf, hb, hb_bf);

  // K+V projection fused: N=512 over [kw;vw]
  mgemm_k<0, 256><<<dim3(512 / 64, M / 64), 256, 0, stream>>>(kv_bf, kwb, Kbf, Vtb, 512,
                                                              nullptr, nullptr, nullptr);

  for (int layer = 0; layer < 2; layer++) {
    attn6_k<<<dim3(BD * HH * (DD / 64)), 256, 0, stream>>>(hb_bf, qwb, qscale, Kbf, Vtb,
                                                           gamma_attn, alibi_strength, hb);
    ln_k<<<M / 4, 256, 0, stream>>>(hb, ln1_w, ln1_b, yb_bf);
    mgemm_k<1, 256><<<dim3((2 * EE) / 64, M / 64), 256, 0, stream>>>(yb_bf, w1b, tb_bf, nullptr,
                                                                     2 * EE, ffn_b1, nullptr, nullptr);
    mgemm_k<2, 512><<<dim3(EE / 64, M / 64), 256, 0, stream>>>(tb_bf, w2b, hb_bf, nullptr,
                                                               EE, ffn_b2, gamma_ffn, hb);
  }

  ln_k<<<M / 4, 256, 0, stream>>>(hb, corr_ln_w, corr_ln_b, yb_bf);
  mgemm_k<1, 256><<<dim3(EE / 64, M / 64), 256, 0, stream>>>(yb_bf, cw1b, tb_bf, nullptr,
                                                             EE, corr_b1, nullptr, nullptr);
  out_k<<<M / 4, 256, 0, stream>>>(tb_bf, corr_w2, corr_b2, (float*)d_out);
}

// Round 12
// 171.159 us; speedup vs baseline: 1.0484x; 1.0484x over previous
//
#include <hip/hip_runtime.h>
#include <math.h>

#define BD 8
#define DD 1024
#define EE 256
#define HH 8
#define HDD 32
#define NBITS 11

typedef __attribute__((ext_vector_type(8))) short short8;
typedef __attribute__((ext_vector_type(4))) float f4;

__device__ __forceinline__ ushort f2bf(float f) {
  unsigned u = __float_as_uint(f);
  u += 0x7fffu + ((u >> 16) & 1u);
  return (ushort)(u >> 16);
}
__device__ __forceinline__ float bf2f(ushort u) {
  return __uint_as_float(((unsigned)u) << 16);
}
__device__ __forceinline__ void async_copy16(ushort* lds, const ushort* g) {
  __builtin_amdgcn_global_load_lds((const __attribute__((address_space(1))) void*)g,
                                   (__attribute__((address_space(3))) void*)lds, 16, 0, 0);
}

// ---------------- prologue: qscale (blocks 0-7) + weight bf16 conversion (blocks 8+) ----------------
// wbf layout: qw[65536] kw[65536] vw[65536] w1[131072] w2[131072] cw1[65536]
__global__ __launch_bounds__(256) void k_pre(const float* __restrict__ x,
                                             const float* __restrict__ film_alpha,
                                             const float* __restrict__ film_a,
                                             float* __restrict__ qscale,
                                             const float* __restrict__ qw,
                                             const float* __restrict__ kw,
                                             const float* __restrict__ vw,
                                             const float* __restrict__ w1,
                                             const float* __restrict__ w2,
                                             const float* __restrict__ cw1,
                                             ushort* __restrict__ o) {
  if (blockIdx.x < 8) {
    __shared__ float red[256];
    int b = blockIdx.x, t = threadIdx.x;
    float s = 0.f;
    #pragma unroll
    for (int i = 0; i < 4; i++) s += x[b * DD + t + i * 256];
    red[t] = s; __syncthreads();
    for (int off = 128; off > 0; off >>= 1) {
      if (t < off) red[t] += red[t + off];
      __syncthreads();
    }
    float total = red[0];
    float ta = tanhf(film_alpha[0]);
    float fa = film_a[0];
    #pragma unroll
    for (int i = 0; i < 4; i++) {
      int d = t + i * 256;
      float xn = (total - x[b * DD + d]) / 1023.0f;
      float qs = 1.0f + ta * tanhf(fa * xn);
      qs = fminf(fmaxf(qs, 0.7f), 1.3f);
      qscale[b * DD + d] = qs;
    }
  } else {
    int i = (int)(blockIdx.x - 8) * 256 + threadIdx.x;
    float v;
    if (i < 65536) v = qw[i];
    else if (i < 131072) v = kw[i - 65536];
    else if (i < 196608) v = vw[i - 131072];
    else if (i < 327680) v = w1[i - 196608];
    else if (i < 458752) v = w2[i - 327680];
    else v = cw1[i - 458752];
    o[i] = f2bf(v);
  }
}

// ---------------- kv/h init with inline pos: kv_bf=bf16(x*vw+vb+pos); h=pos; h_bf=bf16(pos) ----------------
__global__ __launch_bounds__(256) void k_kvh2(const float* __restrict__ x,
                                              const float* __restrict__ value_w,
                                              const float* __restrict__ value_b,
                                              const float* __restrict__ fe,
                                              const float* __restrict__ binary_w,
                                              ushort* __restrict__ kv_bf,
                                              float* __restrict__ h,
                                              ushort* __restrict__ h_bf) {
  int idx = blockIdx.x * 256 + threadIdx.x;   // over B*D*E = 2M
  int e = idx & (EE - 1);
  int d = (idx >> 8) & (DD - 1);
  int b = idx >> 18;
  float p = fe[d * EE + e];
  int code = d + 1;
  #pragma unroll
  for (int bit = 0; bit < NBITS; bit++) {
    float cb = (float)((code >> (NBITS - 1 - bit)) & 1) - 0.5f;
    p += cb * binary_w[e * NBITS + bit];
  }
  kv_bf[idx] = f2bf(x[b * DD + d] * value_w[e] + value_b[e] + p);
  h[idx] = p;
  h_bf[idx] = f2bf(p);
}

// ---------------- MFMA GEMM, double-buffered: C[M,N] = A[M,K] @ W[N,K]^T ----------------
// 64x64 tile, BK=64, 4 waves (2x2), wave tile 32x32; 2-phase LDS prefetch pipeline.
// EPI 0: KV proj -> col<256: K bf16 [B,H,D,32]; col>=256: V bf16 [B,H,32,D] (transposed)
// EPI 1: GELU    -> bf16 [M,N], v = gelu(acc + aux1[col])
// EPI 2: RES     -> hb32[row,col] += aux2[col]*(acc+aux1[col]) (fp32), C = bf16(new hb)
template <int EPI, int KT>
__global__ __launch_bounds__(256) void mgemm_k(const ushort* __restrict__ A,
                                               const ushort* __restrict__ Bw,
                                               ushort* __restrict__ C,
                                               ushort* __restrict__ C2,
                                               int N,
                                               const float* __restrict__ aux1,
                                               const float* __restrict__ aux2,
                                               float* __restrict__ hb32) {
  __shared__ ushort As[2][64 * 64];
  __shared__ ushort Bs[2][64 * 64];
  int tid = threadIdx.x;
  int w = tid >> 6, lane = tid & 63;
  int c = lane & 15, g = lane >> 4;
  int wr = w >> 1, wc = w & 1;
  int lr = lane >> 3, lsl = lane & 7;

  const ushort* Ab = A + (size_t)(blockIdx.y * 64) * KT;
  const ushort* Bb = Bw + (size_t)(blockIdx.x * 64) * KT;

  f4 acc[2][2] = {};
  const int NT = KT / 64;

#define STAGE(buf, kt) do {                                                             \
    _Pragma("unroll")                                                                   \
    for (int j = 0; j < 2; j++) {                                                       \
      int rl = j * 32 + w * 8 + lr;                                                     \
      int slot = lsl ^ (rl & 7);                                                        \
      async_copy16(&As[buf][(j * 32 + w * 8) * 64], Ab + (size_t)rl * KT + (kt) * 64 + slot * 8); \
      async_copy16(&Bs[buf][(j * 32 + w * 8) * 64], Bb + (size_t)rl * KT + (kt) * 64 + slot * 8); \
    } } while (0)

  STAGE(0, 0);
  __syncthreads();   // drain vmcnt(0): tile 0 ready

  #pragma unroll
  for (int kt = 0; kt < NT; kt++) {
    int cur = kt & 1;
    if (kt + 1 < NT) STAGE(cur ^ 1, kt + 1);   // prefetch next tile; latency hides under compute
    #pragma unroll
    for (int ks2 = 0; ks2 < 2; ks2++) {
      short8 af[2], bf_[2];
      #pragma unroll
      for (int mi = 0; mi < 2; mi++) {
        int rowl = wr * 32 + mi * 16 + c;
        int slot = (ks2 * 4 + g) ^ (rowl & 7);
        af[mi] = *(const short8*)&As[cur][rowl * 64 + slot * 8];
      }
      #pragma unroll
      for (int ni = 0; ni < 2; ni++) {
        int rowl = wc * 32 + ni * 16 + c;
        int slot = (ks2 * 4 + g) ^ (rowl & 7);
        bf_[ni] = *(const short8*)&Bs[cur][rowl * 64 + slot * 8];
      }
      #pragma unroll
      for (int mi = 0; mi < 2; mi++)
        #pragma unroll
        for (int ni = 0; ni < 2; ni++)
          acc[mi][ni] = __builtin_amdgcn_mfma_f32_16x16x32_bf16(af[mi], bf_[ni], acc[mi][ni], 0, 0, 0);
    }
    __syncthreads();   // next tile loaded AND everyone done reading buf[cur]
  }
#undef STAGE

  // epilogue: D element (mi,ni,r) -> row = m0+mi*16+4g+r, col = n0+ni*16+c
  int m0 = blockIdx.y * 64 + wr * 32;
  int n0 = blockIdx.x * 64 + wc * 32;
  #pragma unroll
  for (int mi = 0; mi < 2; mi++) {
    #pragma unroll
    for (int ni = 0; ni < 2; ni++) {
      #pragma unroll
      for (int r = 0; r < 4; r++) {
        int row = m0 + mi * 16 + 4 * g + r;
        int col = n0 + ni * 16 + c;
        float v = acc[mi][ni][r];
        if (EPI == 0) {
          int bI = row >> 10, dI = row & 1023;
          if (col < 256) {
            int hI = col >> 5, eI = col & 31;
            C[(((size_t)(bI * HH + hI)) * DD + dI) * HDD + eI] = f2bf(v);
          } else {
            int ch = col - 256;
            int hI = ch >> 5, eI = ch & 31;
            C2[(((size_t)(bI * HH + hI)) * HDD + eI) * DD + dI] = f2bf(v);
          }
        } else if (EPI == 1) {
          v += aux1[col];
          float gl = 0.5f * v * (1.0f + erff(v * 0.70710678118654752f));
          C[(size_t)row * N + col] = f2bf(gl);
        } else if (EPI == 2) {
          v += aux1[col];
          size_t idx = (size_t)row * EE + col;
          float nh = hb32[idx] + aux2[col] * v;
          hb32[idx] = nh;
          C[idx] = f2bf(nh);
        }
      }
    }
  }
}

// ---------------- MFMA flash attention v7: wave-per-head + fused residual + LayerNorm ----------------
// Block = 16 query rows of one batch, 8 waves = 8 heads. Per-wave inner loop identical to the
// verified attn6 (fused Q-proj, swapped QK^T, static softmax, window cut). After all heads finish,
// the block holds the full gamma*attn/l update for its 16x256 slice in LDS -> h_new = h_old + upd
// (single read + write, no RMW), then in-block LayerNorm -> yb_bf. Batch == XCD for K/V locality.
__global__ __launch_bounds__(512) void attn7_k(const ushort* __restrict__ hbf,
                                               const ushort* __restrict__ qwb,
                                               const float* __restrict__ qscale,
                                               const ushort* __restrict__ Kbf,
                                               const ushort* __restrict__ Vtb,
                                               const float* __restrict__ gamma,
                                               const float* __restrict__ strength_p,
                                               float* __restrict__ h,
                                               const float* __restrict__ lnw,
                                               const float* __restrict__ lnb,
                                               ushort* __restrict__ yb) {
  __shared__ __align__(16) ushort Pl[8][16][88];   // per-wave Q staging / P tile
  __shared__ __align__(16) float hs[16][256];      // block's gamma*attn update slice
  int tid = threadIdx.x;
  int w = tid >> 6, lane = tid & 63;
  int c = lane & 15, g = lane >> 4;
  // XCD swizzle: batch b == XCD id; 64 row-chunks of that batch per XCD
  int lid = (blockIdx.x & 7) * 64 + (blockIdx.x >> 3);
  int b = lid >> 6;
  int chunk = lid & 63;
  int hh = w;
  int bh = b * HH + hh;
  int q0 = chunk * 16;
  int qg = q0 + c;
  int dtile = chunk >> 2;                          // 64-key tile containing the diagonal
  float ss = fmaxf(strength_p[0], 0.f) * exp2f(-(float)hh / 8.0f);
  const float L2E = 1.4426950408889634f;

  // ---- fused Q projection: Q[16q x 32e] for this wave's head, K=256 ----
  f4 qa0 = {0.f, 0.f, 0.f, 0.f}, qa1 = {0.f, 0.f, 0.f, 0.f};
  {
    const ushort* Abp = hbf + ((size_t)(b * DD + q0 + c)) * EE + 8 * g;
    const ushort* Bb0 = qwb + ((size_t)(hh * HDD + c)) * EE + 8 * g;
    const ushort* Bb1 = Bb0 + (size_t)16 * EE;
    #pragma unroll
    for (int kk = 0; kk < 8; kk++) {
      short8 a  = *(const short8*)(Abp + kk * 32);
      short8 b0 = *(const short8*)(Bb0 + kk * 32);
      short8 b1 = *(const short8*)(Bb1 + kk * 32);
      qa0 = __builtin_amdgcn_mfma_f32_16x16x32_bf16(a, b0, qa0, 0, 0, 0);
      qa1 = __builtin_amdgcn_mfma_f32_16x16x32_bf16(a, b1, qa1, 0, 0, 0);
    }
  }
  // scale by qscale[row]/sqrt(32), stage via LDS to reach B-operand fragment layout
  {
    const float4 qsv = *(const float4*)&qscale[b * DD + q0 + 4 * g];
    float qs[4] = {qsv.x, qsv.y, qsv.z, qsv.w};
    #pragma unroll
    for (int r = 0; r < 4; r++) {
      float sc = qs[r] * 0.17677669529663687f;
      Pl[w][4 * g + r][c]      = f2bf(qa0[r] * sc);
      Pl[w][4 * g + r][16 + c] = f2bf(qa1[r] * sc);
    }
  }
  // wave-internal LDS write->read is in-order: no barrier needed
  short8 qf = *(const short8*)&Pl[w][c][8 * g];   // lane holds Q[q0+c][8g..8g+7]

  f4 oacc0 = {0.f, 0.f, 0.f, 0.f};
  f4 oacc1 = {0.f, 0.f, 0.f, 0.f};
  float lpart = 0.f;

  const ushort* Kb0 = Kbf + (((size_t)bh * DD + c) << 5) + (g << 3);
  const ushort* Vb0 = Vtb + ((size_t)(bh * HDD + c)) * DD + (g << 3);

  for (int kk = 0; kk < 16; kk++) {
    int ks = (dtile + kk) & 15;
    if (kk) {
      // window cut: relative contribution bound < e^-14 -> negligible
      int dmin = (ks > dtile) ? (ks * 64 - (q0 + 15)) : (q0 - (ks * 64 + 63));
      if (ss * (float)dmin > 14.0f) continue;
    }
    // ---- QK^T (swapped): 4 tiles of 16 keys, S^T[k][q], full K=32 contraction ----
    f4 sa[4];
    #pragma unroll
    for (int t = 0; t < 4; t++) {
      short8 kf = *(const short8*)(Kb0 + (((size_t)(ks * 64 + t * 16)) << 5));
      f4 z = {0.f, 0.f, 0.f, 0.f};
      sa[t] = __builtin_amdgcn_mfma_f32_16x16x32_bf16(kf, qf, z, 0, 0, 0);
    }
    // ---- bias (lane owns query col c; key = ks*64 + t*16 + 4g + r) ----
    float s[16];
    if (kk == 0) {
      #pragma unroll
      for (int t = 0; t < 4; t++) {
        #pragma unroll
        for (int r = 0; r < 4; r++) {
          int k = ks * 64 + t * 16 + 4 * g + r;
          float ad = fabsf((float)(qg - k));
          s[t * 4 + r] = (k == qg) ? -1e30f : fmaf(-ss, ad, sa[t][r]);
        }
      }
    } else {
      float sgn = (ks > dtile) ? -ss : ss;   // bias = sgn*(k - qg), always <= 0
      int kb = ks * 64 + 4 * g - qg;
      #pragma unroll
      for (int t = 0; t < 4; t++) {
        #pragma unroll
        for (int r = 0; r < 4; r++) {
          float dk = (float)(kb + t * 16 + r);
          s[t * 4 + r] = fmaf(sgn, dk, sa[t][r]);
        }
      }
    }
    // ---- static-reference exp (scores provably << 1) + partial sum + truncated bf16 pack ----
    #pragma unroll
    for (int i = 0; i < 16; i++) {
      float p = exp2f(s[i] * L2E);
      s[i] = p;
      lpart += p;
    }
    #pragma unroll
    for (int t = 0; t < 4; t++) {
      uint2 u;
      u.x = __builtin_amdgcn_perm(__float_as_uint(s[t * 4 + 1]), __float_as_uint(s[t * 4 + 0]), 0x07060302u);
      u.y = __builtin_amdgcn_perm(__float_as_uint(s[t * 4 + 3]), __float_as_uint(s[t * 4 + 2]), 0x07060302u);
      *(uint2*)&Pl[w][c][t * 16 + 4 * g] = u;
    }
    // ---- PV: O[q][e] += P[q][k] V[k][e], two K=32 halves, two e-tiles ----
    #pragma unroll
    for (int hb2 = 0; hb2 < 2; hb2++) {
      short8 pa = *(const short8*)&Pl[w][c][hb2 * 32 + 8 * g];
      short8 v0 = *(const short8*)(Vb0 + ks * 64 + hb2 * 32);
      short8 v1 = *(const short8*)(Vb0 + (size_t)16 * DD + ks * 64 + hb2 * 32);
      oacc0 = __builtin_amdgcn_mfma_f32_16x16x32_bf16(pa, v0, oacc0, 0, 0, 0);
      oacc1 = __builtin_amdgcn_mfma_f32_16x16x32_bf16(pa, v1, oacc1, 0, 0, 0);
    }
  }

  // ---- l reduce across the 4 lanes sharing query c ----
  lpart += __shfl_xor(lpart, 16);
  lpart += __shfl_xor(lpart, 32);
  float linv = 1.0f / lpart;

  // ---- deposit gamma * O / l into the block's update slice ----
  #pragma unroll
  for (int r = 0; r < 4; r++) {
    float li = __shfl(linv, 4 * g + r);
    int row = 4 * g + r;
    int e0 = hh * HDD + c, e1 = hh * HDD + 16 + c;
    hs[row][e0] = gamma[e0] * oacc0[r] * li;
    hs[row][e1] = gamma[e1] * oacc1[r] * li;
  }
  __syncthreads();

  // ---- fused residual + LayerNorm: wave w handles rows 2w, 2w+1 ----
  #pragma unroll
  for (int rr = 0; rr < 2; rr++) {
    int row = 2 * w + rr;
    size_t base = ((size_t)(b * DD + q0 + row)) * EE + 4 * lane;
    const float4 ho = *(const float4*)&h[base];
    const float4 ha = *(const float4*)&hs[row][4 * lane];
    float4 v;
    v.x = ho.x + ha.x; v.y = ho.y + ha.y; v.z = ho.z + ha.z; v.w = ho.w + ha.w;
    *(float4*)&h[base] = v;
    float s  = v.x + v.y + v.z + v.w;
    float s2 = v.x * v.x + v.y * v.y + v.z * v.z + v.w * v.w;
    #pragma unroll
    for (int off = 32; off; off >>= 1) {
      s  += __shfl_xor(s, off);
      s2 += __shfl_xor(s2, off);
    }
    float mean = s * (1.0f / EE);
    float var = s2 * (1.0f / EE) - mean * mean;
    float rs = rsqrtf(var + 1e-5f);
    const float4 wv = *(const float4*)&lnw[4 * lane];
    const float4 bv = *(const float4*)&lnb[4 * lane];
    ushort4 o;
    o.x = f2bf((v.x - mean) * rs * wv.x + bv.x);
    o.y = f2bf((v.y - mean) * rs * wv.y + bv.y);
    o.z = f2bf((v.z - mean) * rs * wv.z + bv.z);
    o.w = f2bf((v.w - mean) * rs * wv.w + bv.w);
    *(ushort4*)&yb[base] = o;
  }
}

// ---------------- LayerNorm: one wave per row, float4 + shuffle reduce, no barriers ----------------
__global__ __launch_bounds__(256) void ln_k(const float* __restrict__ hin,
                                            const float* __restrict__ w,
                                            const float* __restrict__ bb,
                                            ushort* __restrict__ y) {
  int row = blockIdx.x * 4 + (threadIdx.x >> 6);
  int lane = threadIdx.x & 63;
  const float4 v = *(const float4*)&hin[(size_t)row * EE + lane * 4];
  float s  = v.x + v.y + v.z + v.w;
  float s2 = v.x * v.x + v.y * v.y + v.z * v.z + v.w * v.w;
  #pragma unroll
  for (int off = 32; off; off >>= 1) {
    s  += __shfl_xor(s, off);
    s2 += __shfl_xor(s2, off);
  }
  float mean = s * (1.0f / EE);
  float var = s2 * (1.0f / EE) - mean * mean;
  float rs = rsqrtf(var + 1e-5f);
  const float4 wv = *(const float4*)&w[lane * 4];
  const float4 bv = *(const float4*)&bb[lane * 4];
  ushort4 o;
  o.x = f2bf((v.x - mean) * rs * wv.x + bv.x);
  o.y = f2bf((v.y - mean) * rs * wv.y + bv.y);
  o.z = f2bf((v.z - mean) * rs * wv.z + bv.z);
  o.w = f2bf((v.w - mean) * rs * wv.w + bv.w);
  *(ushort4*)&y[(size_t)row * EE + lane * 4] = o;
}

// ---------------- final projection to scalar per row ----------------
__global__ __launch_bounds__(256) void out_k(const ushort* __restrict__ t_,
                                             const float* __restrict__ w2,
                                             const float* __restrict__ b2,
                                             float* __restrict__ out) {
  int w = threadIdx.x >> 6, lane = threadIdx.x & 63;
  int r = blockIdx.x * 4 + w;
  float s = 0.f;
  #pragma unroll
  for (int i = 0; i < 4; i++) s += bf2f(t_[(size_t)r * EE + lane + i * 64]) * w2[lane + i * 64];
  #pragma unroll
  for (int off = 32; off; off >>= 1) s += __shfl_xor(s, off);
  if (lane == 0) out[r] = s + b2[0];
}

extern "C" void kernel_launch(void* const* d_in, const int* in_sizes, int n_in,
                              void* d_out, int out_size, void* d_ws, size_t ws_size,
                              hipStream_t stream) {
  const float* x            = (const float*)d_in[0];
  const float* value_w      = (const float*)d_in[1];
  const float* value_b      = (const float*)d_in[2];
  const float* feature_embed= (const float*)d_in[3];
  const float* binary_w     = (const float*)d_in[4];
  const float* qw           = (const float*)d_in[5];
  const float* kw           = (const float*)d_in[6];
  const float* vw           = (const float*)d_in[7];
  const float* film_alpha   = (const float*)d_in[8];
  const float* film_a       = (const float*)d_in[9];
  const float* ln1_w        = (const float*)d_in[10];
  const float* ln1_b        = (const float*)d_in[11];
  const float* ffn_w1       = (const float*)d_in[12];
  const float* ffn_b1       = (const float*)d_in[13];
  const float* ffn_w2       = (const float*)d_in[14];
  const float* ffn_b2       = (const float*)d_in[15];
  const float* gamma_attn   = (const float*)d_in[16];
  const float* gamma_ffn    = (const float*)d_in[17];
  const float* corr_ln_w    = (const float*)d_in[18];
  const float* corr_ln_b    = (const float*)d_in[19];
  const float* corr_w1      = (const float*)d_in[20];
  const float* corr_b1      = (const float*)d_in[21];
  const float* corr_w2      = (const float*)d_in[22];
  const float* corr_b2      = (const float*)d_in[23];
  const float* alibi_strength=(const float*)d_in[24];

  const size_t ME = (size_t)BD * DD * EE;   // 2M
  float* ws = (float*)d_ws;
  float* qscale = ws;                       // 8192 f
  float* hb     = qscale + BD * DD;         // 2M f
  ushort* kv_bf = (ushort*)(hb + ME);       // 2M us
  ushort* hb_bf = kv_bf + ME;               // 2M us
  ushort* yb_bf = hb_bf + ME;               // 2M us
  ushort* tb_bf = yb_bf + ME;               // 4M us
  ushort* Kbf   = tb_bf + 2 * ME;           // 2M us
  ushort* Vtb   = Kbf + ME;                 // 2M us
  ushort* wbf   = Vtb + ME;                 // 524288 us
  ushort* qwb   = wbf;
  ushort* kwb   = wbf + 65536;              // kw rows 0-255, vw rows 256-511 (contiguous)
  ushort* w1b   = wbf + 196608;
  ushort* w2b   = wbf + 327680;
  ushort* cw1b  = wbf + 458752;

  const int M = BD * DD;   // 8192

  k_pre<<<8 + 2048, 256, 0, stream>>>(x, film_alpha, film_a, qscale,
                                      qw, kw, vw, ffn_w1, ffn_w2, corr_w1, wbf);
  k_kvh2<<<(BD * DD * EE) / 256, 256, 0, stream>>>(x, value_w, value_b, feature_embed, binary_w,
                                                   kv_bf, hb, hb_bf);

  // K+V projection fused: N=512 over [kw;vw]
  mgemm_k<0, 256><<<dim3(512 / 64, M / 64), 256, 0, stream>>>(kv_bf, kwb, Kbf, Vtb, 512,
                                                              nullptr, nullptr, nullptr);

  for (int layer = 0; layer < 2; layer++) {
    attn7_k<<<dim3(BD * (DD / 16)), 512, 0, stream>>>(hb_bf, qwb, qscale, Kbf, Vtb,
                                                      gamma_attn, alibi_strength, hb,
                                                      ln1_w, ln1_b, yb_bf);
    mgemm_k<1, 256><<<dim3((2 * EE) / 64, M / 64), 256, 0, stream>>>(yb_bf, w1b, tb_bf, nullptr,
                                                                     2 * EE, ffn_b1, nullptr, nullptr);
    mgemm_k<2, 512><<<dim3(EE / 64, M / 64), 256, 0, stream>>>(tb_bf, w2b, hb_bf, nullptr,
                                                               EE, ffn_b2, gamma_ffn, hb);
  }

  ln_k<<<M / 4, 256, 0, stream>>>(hb, corr_ln_w, corr_ln_b, yb_bf);
  mgemm_k<1, 256><<<dim3(EE / 64, M / 64), 256, 0, stream>>>(yb_bf, cw1b, tb_bf, nullptr,
                                                             EE, corr_b1, nullptr, nullptr);
  out_k<<<M / 4, 256, 0, stream>>>(tb_bf, corr_w2, corr_b2, (float*)d_out);
}

// Round 13
// 167.952 us; speedup vs baseline: 1.0685x; 1.0191x over previous
//
#include <hip/hip_runtime.h>
#include <math.h>

#define BD 8
#define DD 1024
#define EE 256
#define HH 8
#define HDD 32
#define NBITS 11

typedef __attribute__((ext_vector_type(8))) short short8;
typedef __attribute__((ext_vector_type(4))) float f4;

__device__ __forceinline__ ushort f2bf(float f) {
  unsigned u = __float_as_uint(f);
  u += 0x7fffu + ((u >> 16) & 1u);
  return (ushort)(u >> 16);
}
__device__ __forceinline__ float bf2f(ushort u) {
  return __uint_as_float(((unsigned)u) << 16);
}
__device__ __forceinline__ void async_copy16(ushort* lds, const ushort* g) {
  __builtin_amdgcn_global_load_lds((const __attribute__((address_space(1))) void*)g,
                                   (__attribute__((address_space(3))) void*)lds, 16, 0, 0);
}

// ---------------- fused prologue ----------------
// blocks 0..8191: kv/h init (pos inline); 8192..8199: qscale; 8200..10247: weight bf16 conv
__global__ __launch_bounds__(256) void k_pro(const float* __restrict__ x,
                                             const float* __restrict__ value_w,
                                             const float* __restrict__ value_b,
                                             const float* __restrict__ fe,
                                             const float* __restrict__ binary_w,
                                             ushort* __restrict__ kv_bf,
                                             float* __restrict__ h,
                                             ushort* __restrict__ h_bf,
                                             const float* __restrict__ film_alpha,
                                             const float* __restrict__ film_a,
                                             float* __restrict__ qscale,
                                             const float* __restrict__ qw,
                                             const float* __restrict__ kw,
                                             const float* __restrict__ vw,
                                             const float* __restrict__ w1,
                                             const float* __restrict__ w2,
                                             const float* __restrict__ cw1,
                                             ushort* __restrict__ o) {
  if (blockIdx.x < 8192) {
    int idx = blockIdx.x * 256 + threadIdx.x;   // over B*D*E = 2M
    int e = idx & (EE - 1);
    int d = (idx >> 8) & (DD - 1);
    int b = idx >> 18;
    float p = fe[d * EE + e];
    int code = d + 1;
    #pragma unroll
    for (int bit = 0; bit < NBITS; bit++) {
      float cb = (float)((code >> (NBITS - 1 - bit)) & 1) - 0.5f;
      p += cb * binary_w[e * NBITS + bit];
    }
    kv_bf[idx] = f2bf(x[b * DD + d] * value_w[e] + value_b[e] + p);
    h[idx] = p;
    h_bf[idx] = f2bf(p);
  } else if (blockIdx.x < 8200) {
    __shared__ float red[256];
    int b = blockIdx.x - 8192, t = threadIdx.x;
    float s = 0.f;
    #pragma unroll
    for (int i = 0; i < 4; i++) s += x[b * DD + t + i * 256];
    red[t] = s; __syncthreads();
    for (int off = 128; off > 0; off >>= 1) {
      if (t < off) red[t] += red[t + off];
      __syncthreads();
    }
    float total = red[0];
    float ta = tanhf(film_alpha[0]);
    float fa = film_a[0];
    #pragma unroll
    for (int i = 0; i < 4; i++) {
      int d = t + i * 256;
      float xn = (total - x[b * DD + d]) / 1023.0f;
      float qs = 1.0f + ta * tanhf(fa * xn);
      qs = fminf(fmaxf(qs, 0.7f), 1.3f);
      qscale[b * DD + d] = qs;
    }
  } else {
    int i = (int)(blockIdx.x - 8200) * 256 + threadIdx.x;
    float v;
    if (i < 65536) v = qw[i];
    else if (i < 131072) v = kw[i - 65536];
    else if (i < 196608) v = vw[i - 131072];
    else if (i < 327680) v = w1[i - 196608];
    else if (i < 458752) v = w2[i - 327680];
    else v = cw1[i - 458752];
    o[i] = f2bf(v);
  }
}

// ---------------- MFMA GEMM, 128x64 tile, 8 waves, double-buffered ----------------
// C[M,N] = A[M,K] @ W[N,K]^T; BM=128, BN=64, BK=64; wave grid 4x2, wave tile 32x32.
// EPI 0: KV proj -> col<256: K bf16 [B,H,D,32]; col>=256: V bf16 [B,H,32,D] (transposed)
// EPI 1: GELU    -> bf16 [M,N], v = gelu(acc + aux1[col])
// EPI 2: RES     -> hb32[row,col] += aux2[col]*(acc+aux1[col]) (fp32), C = bf16(new hb)
template <int EPI, int KT>
__global__ __launch_bounds__(512) void mgemm_k(const ushort* __restrict__ A,
                                               const ushort* __restrict__ Bw,
                                               ushort* __restrict__ C,
                                               ushort* __restrict__ C2,
                                               int N,
                                               const float* __restrict__ aux1,
                                               const float* __restrict__ aux2,
                                               float* __restrict__ hb32) {
  __shared__ ushort As[2][128 * 64];
  __shared__ ushort Bs[2][64 * 64];
  int tid = threadIdx.x;
  int w = tid >> 6, lane = tid & 63;
  int c = lane & 15, g = lane >> 4;
  int wr = w >> 1, wc = w & 1;
  int lr = lane >> 3, lsl = lane & 7;

  const ushort* Ab = A + (size_t)(blockIdx.y * 128) * KT;
  const ushort* Bb = Bw + (size_t)(blockIdx.x * 64) * KT;

  f4 acc[2][2] = {};
  const int NT = KT / 64;

#define STAGE(buf, kt) do {                                                                   \
    _Pragma("unroll")                                                                         \
    for (int j = 0; j < 2; j++) {                                                             \
      int rl = j * 64 + w * 8 + lr;                                                           \
      int slot = lsl ^ (rl & 7);                                                              \
      async_copy16(&As[buf][(j * 64 + w * 8) * 64], Ab + (size_t)rl * KT + (kt) * 64 + slot * 8); \
    }                                                                                         \
    { int rl = w * 8 + lr; int slot = lsl ^ (rl & 7);                                         \
      async_copy16(&Bs[buf][(w * 8) * 64], Bb + (size_t)rl * KT + (kt) * 64 + slot * 8); }    \
  } while (0)

  STAGE(0, 0);
  __syncthreads();   // drain vmcnt(0): tile 0 ready

  #pragma unroll
  for (int kt = 0; kt < NT; kt++) {
    int cur = kt & 1;
    if (kt + 1 < NT) STAGE(cur ^ 1, kt + 1);   // prefetch next tile under compute
    #pragma unroll
    for (int ks2 = 0; ks2 < 2; ks2++) {
      short8 af[2], bf_[2];
      #pragma unroll
      for (int mi = 0; mi < 2; mi++) {
        int rowl = wr * 32 + mi * 16 + c;
        int slot = (ks2 * 4 + g) ^ (rowl & 7);
        af[mi] = *(const short8*)&As[cur][rowl * 64 + slot * 8];
      }
      #pragma unroll
      for (int ni = 0; ni < 2; ni++) {
        int rowl = wc * 32 + ni * 16 + c;
        int slot = (ks2 * 4 + g) ^ (rowl & 7);
        bf_[ni] = *(const short8*)&Bs[cur][rowl * 64 + slot * 8];
      }
      #pragma unroll
      for (int mi = 0; mi < 2; mi++)
        #pragma unroll
        for (int ni = 0; ni < 2; ni++)
          acc[mi][ni] = __builtin_amdgcn_mfma_f32_16x16x32_bf16(af[mi], bf_[ni], acc[mi][ni], 0, 0, 0);
    }
    __syncthreads();
  }
#undef STAGE

  int m0 = blockIdx.y * 128 + wr * 32;
  int n0 = blockIdx.x * 64 + wc * 32;
  #pragma unroll
  for (int mi = 0; mi < 2; mi++) {
    #pragma unroll
    for (int ni = 0; ni < 2; ni++) {
      #pragma unroll
      for (int r = 0; r < 4; r++) {
        int row = m0 + mi * 16 + 4 * g + r;
        int col = n0 + ni * 16 + c;
        float v = acc[mi][ni][r];
        if (EPI == 0) {
          int bI = row >> 10, dI = row & 1023;
          if (col < 256) {
            int hI = col >> 5, eI = col & 31;
            C[(((size_t)(bI * HH + hI)) * DD + dI) * HDD + eI] = f2bf(v);
          } else {
            int ch = col - 256;
            int hI = ch >> 5, eI = ch & 31;
            C2[(((size_t)(bI * HH + hI)) * HDD + eI) * DD + dI] = f2bf(v);
          }
        } else if (EPI == 1) {
          v += aux1[col];
          float gl = 0.5f * v * (1.0f + erff(v * 0.70710678118654752f));
          C[(size_t)row * N + col] = f2bf(gl);
        } else if (EPI == 2) {
          v += aux1[col];
          size_t idx = (size_t)row * EE + col;
          float nh = hb32[idx] + aux2[col] * v;
          hb32[idx] = nh;
          C[idx] = f2bf(nh);
        }
      }
    }
  }
}

// ---------------- MFMA flash attention v8: banded tile loop + K/V prefetch + fused res+LN ----------------
// Block = 16 query rows of one batch, 8 waves = 8 heads. Static softmax (scores << 1, bias <= 0).
// Tile band [lo,hi] from the window cut (monotone in distance -> contiguous). K fragments preloaded
// one tile ahead; V loads issued before the softmax VALU chain so L2 latency hides under exp/pack.
__global__ __launch_bounds__(512) void attn8_k(const ushort* __restrict__ hbf,
                                               const ushort* __restrict__ qwb,
                                               const float* __restrict__ qscale,
                                               const ushort* __restrict__ Kbf,
                                               const ushort* __restrict__ Vtb,
                                               const float* __restrict__ gamma,
                                               const float* __restrict__ strength_p,
                                               float* __restrict__ h,
                                               const float* __restrict__ lnw,
                                               const float* __restrict__ lnb,
                                               ushort* __restrict__ yb) {
  __shared__ __align__(16) ushort Pl[8][16][88];   // per-wave Q staging / P tile
  __shared__ __align__(16) float hs[16][256];      // block's gamma*attn update slice
  int tid = threadIdx.x;
  int w = tid >> 6, lane = tid & 63;
  int c = lane & 15, g = lane >> 4;
  // XCD swizzle: batch b == XCD id
  int lid = (blockIdx.x & 7) * 64 + (blockIdx.x >> 3);
  int b = lid >> 6;
  int chunk = lid & 63;
  int hh = w;
  int bh = b * HH + hh;
  int q0 = chunk * 16;
  int qg = q0 + c;
  int dtile = chunk >> 2;
  float ss = fmaxf(strength_p[0], 0.f) * exp2f(-(float)hh / 8.0f);
  const float L2E = 1.4426950408889634f;

  // ---- fused Q projection: Q[16q x 32e] for this wave's head, K=256 ----
  f4 qa0 = {0.f, 0.f, 0.f, 0.f}, qa1 = {0.f, 0.f, 0.f, 0.f};
  {
    const ushort* Abp = hbf + ((size_t)(b * DD + q0 + c)) * EE + 8 * g;
    const ushort* Bb0 = qwb + ((size_t)(hh * HDD + c)) * EE + 8 * g;
    const ushort* Bb1 = Bb0 + (size_t)16 * EE;
    #pragma unroll
    for (int kk = 0; kk < 8; kk++) {
      short8 a  = *(const short8*)(Abp + kk * 32);
      short8 b0 = *(const short8*)(Bb0 + kk * 32);
      short8 b1 = *(const short8*)(Bb1 + kk * 32);
      qa0 = __builtin_amdgcn_mfma_f32_16x16x32_bf16(a, b0, qa0, 0, 0, 0);
      qa1 = __builtin_amdgcn_mfma_f32_16x16x32_bf16(a, b1, qa1, 0, 0, 0);
    }
  }
  {
    const float4 qsv = *(const float4*)&qscale[b * DD + q0 + 4 * g];
    float qs[4] = {qsv.x, qsv.y, qsv.z, qsv.w};
    #pragma unroll
    for (int r = 0; r < 4; r++) {
      float sc = qs[r] * 0.17677669529663687f;
      Pl[w][4 * g + r][c]      = f2bf(qa0[r] * sc);
      Pl[w][4 * g + r][16 + c] = f2bf(qa1[r] * sc);
    }
  }
  // wave-internal LDS write->read is in-order
  short8 qf = *(const short8*)&Pl[w][c][8 * g];

  // ---- tile band from window cut: keep tiles with relative contribution >= e^-14 ----
  int Wi = (ss > 1e-8f) ? (int)fminf(14.0f / ss, 1.0e6f) : 1000000;
  int hi = min(15, (q0 + 15 + Wi) >> 6);
  int tlo = q0 - 63 - Wi;
  int lo = (tlo <= 0) ? 0 : ((tlo + 63) >> 6);

  f4 oacc0 = {0.f, 0.f, 0.f, 0.f};
  f4 oacc1 = {0.f, 0.f, 0.f, 0.f};
  float lpart = 0.f;

  const ushort* Kb0 = Kbf + (((size_t)bh * DD + c) << 5) + (g << 3);
  const ushort* Vb0 = Vtb + ((size_t)(bh * HDD + c)) * DD + (g << 3);

  // preload K fragments for the first tile
  short8 kf0 = *(const short8*)(Kb0 + (((size_t)(lo * 64 + 0))  << 5));
  short8 kf1 = *(const short8*)(Kb0 + (((size_t)(lo * 64 + 16)) << 5));
  short8 kf2 = *(const short8*)(Kb0 + (((size_t)(lo * 64 + 32)) << 5));
  short8 kf3 = *(const short8*)(Kb0 + (((size_t)(lo * 64 + 48)) << 5));

  for (int ks = lo; ks <= hi; ks++) {
    // early V loads: in flight across the whole softmax chain
    const ushort* vb = Vb0 + ks * 64;
    short8 va0 = *(const short8*)(vb);
    short8 va1 = *(const short8*)(vb + 32);
    short8 vc0 = *(const short8*)(vb + (size_t)16 * DD);
    short8 vc1 = *(const short8*)(vb + (size_t)16 * DD + 32);
    // QK^T (swapped): S^T[k][q]
    f4 z = {0.f, 0.f, 0.f, 0.f};
    f4 sa[4];
    sa[0] = __builtin_amdgcn_mfma_f32_16x16x32_bf16(kf0, qf, z, 0, 0, 0);
    sa[1] = __builtin_amdgcn_mfma_f32_16x16x32_bf16(kf1, qf, z, 0, 0, 0);
    sa[2] = __builtin_amdgcn_mfma_f32_16x16x32_bf16(kf2, qf, z, 0, 0, 0);
    sa[3] = __builtin_amdgcn_mfma_f32_16x16x32_bf16(kf3, qf, z, 0, 0, 0);
    // prefetch next tile's K fragments (hides under softmax VALU)
    if (ks < hi) {
      const ushort* kb = Kb0 + (((size_t)((ks + 1) * 64)) << 5);
      kf0 = *(const short8*)(kb);
      kf1 = *(const short8*)(kb + (16 << 5));
      kf2 = *(const short8*)(kb + (32 << 5));
      kf3 = *(const short8*)(kb + (48 << 5));
    }
    // bias (lane owns query col c; key = ks*64 + t*16 + 4g + r)
    float s[16];
    if (ks == dtile) {
      #pragma unroll
      for (int t = 0; t < 4; t++) {
        #pragma unroll
        for (int r = 0; r < 4; r++) {
          int k = ks * 64 + t * 16 + 4 * g + r;
          float ad = fabsf((float)(qg - k));
          s[t * 4 + r] = (k == qg) ? -1e30f : fmaf(-ss, ad, sa[t][r]);
        }
      }
    } else {
      float sgn = (ks > dtile) ? -ss : ss;   // bias = sgn*(k - qg) <= 0
      int kb2 = ks * 64 + 4 * g - qg;
      #pragma unroll
      for (int t = 0; t < 4; t++) {
        #pragma unroll
        for (int r = 0; r < 4; r++) {
          float dk = (float)(kb2 + t * 16 + r);
          s[t * 4 + r] = fmaf(sgn, dk, sa[t][r]);
        }
      }
    }
    // static-reference exp + partial sum + truncated bf16 pack
    #pragma unroll
    for (int i = 0; i < 16; i++) {
      float p = exp2f(s[i] * L2E);
      s[i] = p;
      lpart += p;
    }
    #pragma unroll
    for (int t = 0; t < 4; t++) {
      uint2 u;
      u.x = __builtin_amdgcn_perm(__float_as_uint(s[t * 4 + 1]), __float_as_uint(s[t * 4 + 0]), 0x07060302u);
      u.y = __builtin_amdgcn_perm(__float_as_uint(s[t * 4 + 3]), __float_as_uint(s[t * 4 + 2]), 0x07060302u);
      *(uint2*)&Pl[w][c][t * 16 + 4 * g] = u;
    }
    // PV: O[q][e] += P[q][k] V[k][e]
    short8 pa0 = *(const short8*)&Pl[w][c][8 * g];
    short8 pa1 = *(const short8*)&Pl[w][c][32 + 8 * g];
    oacc0 = __builtin_amdgcn_mfma_f32_16x16x32_bf16(pa0, va0, oacc0, 0, 0, 0);
    oacc1 = __builtin_amdgcn_mfma_f32_16x16x32_bf16(pa0, vc0, oacc1, 0, 0, 0);
    oacc0 = __builtin_amdgcn_mfma_f32_16x16x32_bf16(pa1, va1, oacc0, 0, 0, 0);
    oacc1 = __builtin_amdgcn_mfma_f32_16x16x32_bf16(pa1, vc1, oacc1, 0, 0, 0);
  }

  // ---- l reduce across the 4 lanes sharing query c ----
  lpart += __shfl_xor(lpart, 16);
  lpart += __shfl_xor(lpart, 32);
  float linv = 1.0f / lpart;

  // ---- deposit gamma * O / l into the block's update slice ----
  #pragma unroll
  for (int r = 0; r < 4; r++) {
    float li = __shfl(linv, 4 * g + r);
    int row = 4 * g + r;
    int e0 = hh * HDD + c, e1 = hh * HDD + 16 + c;
    hs[row][e0] = gamma[e0] * oacc0[r] * li;
    hs[row][e1] = gamma[e1] * oacc1[r] * li;
  }
  __syncthreads();

  // ---- fused residual + LayerNorm: wave w handles rows 2w, 2w+1 ----
  #pragma unroll
  for (int rr = 0; rr < 2; rr++) {
    int row = 2 * w + rr;
    size_t base = ((size_t)(b * DD + q0 + row)) * EE + 4 * lane;
    const float4 ho = *(const float4*)&h[base];
    const float4 ha = *(const float4*)&hs[row][4 * lane];
    float4 v;
    v.x = ho.x + ha.x; v.y = ho.y + ha.y; v.z = ho.z + ha.z; v.w = ho.w + ha.w;
    *(float4*)&h[base] = v;
    float s  = v.x + v.y + v.z + v.w;
    float s2 = v.x * v.x + v.y * v.y + v.z * v.z + v.w * v.w;
    #pragma unroll
    for (int off = 32; off; off >>= 1) {
      s  += __shfl_xor(s, off);
      s2 += __shfl_xor(s2, off);
    }
    float mean = s * (1.0f / EE);
    float var = s2 * (1.0f / EE) - mean * mean;
    float rs = rsqrtf(var + 1e-5f);
    const float4 wv = *(const float4*)&lnw[4 * lane];
    const float4 bv = *(const float4*)&lnb[4 * lane];
    ushort4 o;
    o.x = f2bf((v.x - mean) * rs * wv.x + bv.x);
    o.y = f2bf((v.y - mean) * rs * wv.y + bv.y);
    o.z = f2bf((v.z - mean) * rs * wv.z + bv.z);
    o.w = f2bf((v.w - mean) * rs * wv.w + bv.w);
    *(ushort4*)&yb[base] = o;
  }
}

// ---------------- LayerNorm: one wave per row, float4 + shuffle reduce ----------------
__global__ __launch_bounds__(256) void ln_k(const float* __restrict__ hin,
                                            const float* __restrict__ w,
                                            const float* __restrict__ bb,
                                            ushort* __restrict__ y) {
  int row = blockIdx.x * 4 + (threadIdx.x >> 6);
  int lane = threadIdx.x & 63;
  const float4 v = *(const float4*)&hin[(size_t)row * EE + lane * 4];
  float s  = v.x + v.y + v.z + v.w;
  float s2 = v.x * v.x + v.y * v.y + v.z * v.z + v.w * v.w;
  #pragma unroll
  for (int off = 32; off; off >>= 1) {
    s  += __shfl_xor(s, off);
    s2 += __shfl_xor(s2, off);
  }
  float mean = s * (1.0f / EE);
  float var = s2 * (1.0f / EE) - mean * mean;
  float rs = rsqrtf(var + 1e-5f);
  const float4 wv = *(const float4*)&w[lane * 4];
  const float4 bv = *(const float4*)&bb[lane * 4];
  ushort4 o;
  o.x = f2bf((v.x - mean) * rs * wv.x + bv.x);
  o.y = f2bf((v.y - mean) * rs * wv.y + bv.y);
  o.z = f2bf((v.z - mean) * rs * wv.z + bv.z);
  o.w = f2bf((v.w - mean) * rs * wv.w + bv.w);
  *(ushort4*)&y[(size_t)row * EE + lane * 4] = o;
}

// ---------------- final projection to scalar per row ----------------
__global__ __launch_bounds__(256) void out_k(const ushort* __restrict__ t_,
                                             const float* __restrict__ w2,
                                             const float* __restrict__ b2,
                                             float* __restrict__ out) {
  int w = threadIdx.x >> 6, lane = threadIdx.x & 63;
  int r = blockIdx.x * 4 + w;
  float s = 0.f;
  #pragma unroll
  for (int i = 0; i < 4; i++) s += bf2f(t_[(size_t)r * EE + lane + i * 64]) * w2[lane + i * 64];
  #pragma unroll
  for (int off = 32; off; off >>= 1) s += __shfl_xor(s, off);
  if (lane == 0) out[r] = s + b2[0];
}

extern "C" void kernel_launch(void* const* d_in, const int* in_sizes, int n_in,
                              void* d_out, int out_size, void* d_ws, size_t ws_size,
                              hipStream_t stream) {
  const float* x            = (const float*)d_in[0];
  const float* value_w      = (const float*)d_in[1];
  const float* value_b      = (const float*)d_in[2];
  const float* feature_embed= (const float*)d_in[3];
  const float* binary_w     = (const float*)d_in[4];
  const float* qw           = (const float*)d_in[5];
  const float* kw           = (const float*)d_in[6];
  const float* vw           = (const float*)d_in[7];
  const float* film_alpha   = (const float*)d_in[8];
  const float* film_a       = (const float*)d_in[9];
  const float* ln1_w        = (const float*)d_in[10];
  const float* ln1_b        = (const float*)d_in[11];
  const float* ffn_w1       = (const float*)d_in[12];
  const float* ffn_b1       = (const float*)d_in[13];
  const float* ffn_w2       = (const float*)d_in[14];
  const float* ffn_b2       = (const float*)d_in[15];
  const float* gamma_attn   = (const float*)d_in[16];
  const float* gamma_ffn    = (const float*)d_in[17];
  const float* corr_ln_w    = (const float*)d_in[18];
  const float* corr_ln_b    = (const float*)d_in[19];
  const float* corr_w1      = (const float*)d_in[20];
  const float* corr_b1      = (const float*)d_in[21];
  const float* corr_w2      = (const float*)d_in[22];
  const float* corr_b2      = (const float*)d_in[23];
  const float* alibi_strength=(const float*)d_in[24];

  const size_t ME = (size_t)BD * DD * EE;   // 2M
  float* ws = (float*)d_ws;
  float* qscale = ws;                       // 8192 f
  float* hb     = qscale + BD * DD;         // 2M f
  ushort* kv_bf = (ushort*)(hb + ME);       // 2M us
  ushort* hb_bf = kv_bf + ME;               // 2M us
  ushort* yb_bf = hb_bf + ME;               // 2M us
  ushort* tb_bf = yb_bf + ME;               // 4M us
  ushort* Kbf   = tb_bf + 2 * ME;           // 2M us
  ushort* Vtb   = Kbf + ME;                 // 2M us
  ushort* wbf   = Vtb + ME;                 // 524288 us
  ushort* qwb   = wbf;
  ushort* kwb   = wbf + 65536;              // kw rows 0-255, vw rows 256-511 (contiguous)
  ushort* w1b   = wbf + 196608;
  ushort* w2b   = wbf + 327680;
  ushort* cw1b  = wbf + 458752;

  const int M = BD * DD;   // 8192

  k_pro<<<8192 + 8 + 2048, 256, 0, stream>>>(x, value_w, value_b, feature_embed, binary_w,
                                             kv_bf, hb, hb_bf,
                                             film_alpha, film_a, qscale,
                                             qw, kw, vw, ffn_w1, ffn_w2, corr_w1, wbf);

  // K+V projection fused: N=512 over [kw;vw]
  mgemm_k<0, 256><<<dim3(512 / 64, M / 128), 512, 0, stream>>>(kv_bf, kwb, Kbf, Vtb, 512,
                                                               nullptr, nullptr, nullptr);

  for (int layer = 0; layer < 2; layer++) {
    attn8_k<<<dim3(BD * (DD / 16)), 512, 0, stream>>>(hb_bf, qwb, qscale, Kbf, Vtb,
                                                      gamma_attn, alibi_strength, hb,
                                                      ln1_w, ln1_b, yb_bf);
    mgemm_k<1, 256><<<dim3((2 * EE) / 64, M / 128), 512, 0, stream>>>(yb_bf, w1b, tb_bf, nullptr,
                                                                      2 * EE, ffn_b1, nullptr, nullptr);
    mgemm_k<2, 512><<<dim3(EE / 64, M / 128), 512, 0, stream>>>(tb_bf, w2b, hb_bf, nullptr,
                                                                EE, ffn_b2, gamma_ffn, hb);
  }

  ln_k<<<M / 4, 256, 0, stream>>>(hb, corr_ln_w, corr_ln_b, yb_bf);
  mgemm_k<1, 256><<<dim3(EE / 64, M / 128), 512, 0, stream>>>(yb_bf, cw1b, tb_bf, nullptr,
                                                              EE, corr_b1, nullptr, nullptr);
  out_k<<<M / 4, 256, 0, stream>>>(tb_bf, corr_w2, corr_b2, (float*)d_out);
}

// Round 14
// 160.829 us; speedup vs baseline: 1.1158x; 1.0443x over previous
//
#include <hip/hip_runtime.h>
#include <math.h>

#define BD 8
#define DD 1024
#define EE 256
#define HH 8
#define HDD 32
#define NBITS 11

typedef __attribute__((ext_vector_type(8))) short short8;
typedef __attribute__((ext_vector_type(4))) float f4;

__device__ __forceinline__ ushort f2bf(float f) {
  unsigned u = __float_as_uint(f);
  u += 0x7fffu + ((u >> 16) & 1u);
  return (ushort)(u >> 16);
}
__device__ __forceinline__ float bf2f(ushort u) {
  return __uint_as_float(((unsigned)u) << 16);
}
__device__ __forceinline__ void async_copy16(ushort* lds, const ushort* g) {
  __builtin_amdgcn_global_load_lds((const __attribute__((address_space(1))) void*)g,
                                   (__attribute__((address_space(3))) void*)lds, 16, 0, 0);
}

// ---------------- fused prologue ----------------
// blocks 0..8191: kv/h init (pos inline); 8192..8199: qscale; 8200..10247: weight bf16 conv
__global__ __launch_bounds__(256) void k_pro(const float* __restrict__ x,
                                             const float* __restrict__ value_w,
                                             const float* __restrict__ value_b,
                                             const float* __restrict__ fe,
                                             const float* __restrict__ binary_w,
                                             ushort* __restrict__ kv_bf,
                                             float* __restrict__ h,
                                             ushort* __restrict__ h_bf,
                                             const float* __restrict__ film_alpha,
                                             const float* __restrict__ film_a,
                                             float* __restrict__ qscale,
                                             const float* __restrict__ qw,
                                             const float* __restrict__ kw,
                                             const float* __restrict__ vw,
                                             const float* __restrict__ w1,
                                             const float* __restrict__ w2,
                                             const float* __restrict__ cw1,
                                             ushort* __restrict__ o) {
  if (blockIdx.x < 8192) {
    int idx = blockIdx.x * 256 + threadIdx.x;   // over B*D*E = 2M
    int e = idx & (EE - 1);
    int d = (idx >> 8) & (DD - 1);
    int b = idx >> 18;
    float p = fe[d * EE + e];
    int code = d + 1;
    #pragma unroll
    for (int bit = 0; bit < NBITS; bit++) {
      float cb = (float)((code >> (NBITS - 1 - bit)) & 1) - 0.5f;
      p += cb * binary_w[e * NBITS + bit];
    }
    kv_bf[idx] = f2bf(x[b * DD + d] * value_w[e] + value_b[e] + p);
    h[idx] = p;
    h_bf[idx] = f2bf(p);
  } else if (blockIdx.x < 8200) {
    __shared__ float red[256];
    int b = blockIdx.x - 8192, t = threadIdx.x;
    float s = 0.f;
    #pragma unroll
    for (int i = 0; i < 4; i++) s += x[b * DD + t + i * 256];
    red[t] = s; __syncthreads();
    for (int off = 128; off > 0; off >>= 1) {
      if (t < off) red[t] += red[t + off];
      __syncthreads();
    }
    float total = red[0];
    float ta = tanhf(film_alpha[0]);
    float fa = film_a[0];
    #pragma unroll
    for (int i = 0; i < 4; i++) {
      int d = t + i * 256;
      float xn = (total - x[b * DD + d]) / 1023.0f;
      float qs = 1.0f + ta * tanhf(fa * xn);
      qs = fminf(fmaxf(qs, 0.7f), 1.3f);
      qscale[b * DD + d] = qs;
    }
  } else {
    int i = (int)(blockIdx.x - 8200) * 256 + threadIdx.x;
    float v;
    if (i < 65536) v = qw[i];
    else if (i < 131072) v = kw[i - 65536];
    else if (i < 196608) v = vw[i - 131072];
    else if (i < 327680) v = w1[i - 196608];
    else if (i < 458752) v = w2[i - 327680];
    else v = cw1[i - 458752];
    o[i] = f2bf(v);
  }
}

// ---------------- MFMA GEMM, 128x64 tile, 8 waves, double-buffered ----------------
// C[M,N] = A[M,K] @ W[N,K]^T; BM=128, BN=64, BK=64; wave grid 4x2, wave tile 32x32.
// EPI 0: KV proj -> col<256: K bf16 [B,H,D,32]; col>=256: V bf16 [B,H,32,D] (transposed)
// EPI 1: GELU    -> bf16 [M,N], v = gelu(acc + aux1[col])
// EPI 2: RES     -> hb32[row,col] += aux2[col]*(acc+aux1[col]) (fp32), C = bf16(new hb)
template <int EPI, int KT>
__global__ __launch_bounds__(512) void mgemm_k(const ushort* __restrict__ A,
                                               const ushort* __restrict__ Bw,
                                               ushort* __restrict__ C,
                                               ushort* __restrict__ C2,
                                               int N,
                                               const float* __restrict__ aux1,
                                               const float* __restrict__ aux2,
                                               float* __restrict__ hb32) {
  __shared__ ushort As[2][128 * 64];
  __shared__ ushort Bs[2][64 * 64];
  int tid = threadIdx.x;
  int w = tid >> 6, lane = tid & 63;
  int c = lane & 15, g = lane >> 4;
  int wr = w >> 1, wc = w & 1;
  int lr = lane >> 3, lsl = lane & 7;

  const ushort* Ab = A + (size_t)(blockIdx.y * 128) * KT;
  const ushort* Bb = Bw + (size_t)(blockIdx.x * 64) * KT;

  f4 acc[2][2] = {};
  const int NT = KT / 64;

#define STAGE(buf, kt) do {                                                                   \
    _Pragma("unroll")                                                                         \
    for (int j = 0; j < 2; j++) {                                                             \
      int rl = j * 64 + w * 8 + lr;                                                           \
      int slot = lsl ^ (rl & 7);                                                              \
      async_copy16(&As[buf][(j * 64 + w * 8) * 64], Ab + (size_t)rl * KT + (kt) * 64 + slot * 8); \
    }                                                                                         \
    { int rl = w * 8 + lr; int slot = lsl ^ (rl & 7);                                         \
      async_copy16(&Bs[buf][(w * 8) * 64], Bb + (size_t)rl * KT + (kt) * 64 + slot * 8); }    \
  } while (0)

  STAGE(0, 0);
  __syncthreads();   // drain vmcnt(0): tile 0 ready

  #pragma unroll
  for (int kt = 0; kt < NT; kt++) {
    int cur = kt & 1;
    if (kt + 1 < NT) STAGE(cur ^ 1, kt + 1);   // prefetch next tile under compute
    #pragma unroll
    for (int ks2 = 0; ks2 < 2; ks2++) {
      short8 af[2], bf_[2];
      #pragma unroll
      for (int mi = 0; mi < 2; mi++) {
        int rowl = wr * 32 + mi * 16 + c;
        int slot = (ks2 * 4 + g) ^ (rowl & 7);
        af[mi] = *(const short8*)&As[cur][rowl * 64 + slot * 8];
      }
      #pragma unroll
      for (int ni = 0; ni < 2; ni++) {
        int rowl = wc * 32 + ni * 16 + c;
        int slot = (ks2 * 4 + g) ^ (rowl & 7);
        bf_[ni] = *(const short8*)&Bs[cur][rowl * 64 + slot * 8];
      }
      #pragma unroll
      for (int mi = 0; mi < 2; mi++)
        #pragma unroll
        for (int ni = 0; ni < 2; ni++)
          acc[mi][ni] = __builtin_amdgcn_mfma_f32_16x16x32_bf16(af[mi], bf_[ni], acc[mi][ni], 0, 0, 0);
    }
    __syncthreads();
  }
#undef STAGE

  int m0 = blockIdx.y * 128 + wr * 32;
  int n0 = blockIdx.x * 64 + wc * 32;
  #pragma unroll
  for (int mi = 0; mi < 2; mi++) {
    #pragma unroll
    for (int ni = 0; ni < 2; ni++) {
      #pragma unroll
      for (int r = 0; r < 4; r++) {
        int row = m0 + mi * 16 + 4 * g + r;
        int col = n0 + ni * 16 + c;
        float v = acc[mi][ni][r];
        if (EPI == 0) {
          int bI = row >> 10, dI = row & 1023;
          if (col < 256) {
            int hI = col >> 5, eI = col & 31;
            C[(((size_t)(bI * HH + hI)) * DD + dI) * HDD + eI] = f2bf(v);
          } else {
            int ch = col - 256;
            int hI = ch >> 5, eI = ch & 31;
            C2[(((size_t)(bI * HH + hI)) * HDD + eI) * DD + dI] = f2bf(v);
          }
        } else if (EPI == 1) {
          v += aux1[col];
          float gl = 0.5f * v * (1.0f + erff(v * 0.70710678118654752f));
          C[(size_t)row * N + col] = f2bf(gl);
        } else if (EPI == 2) {
          v += aux1[col];
          size_t idx = (size_t)row * EE + col;
          float nh = hb32[idx] + aux2[col] * v;
          hb32[idx] = nh;
          C[idx] = f2bf(nh);
        }
      }
    }
  }
}

// ---------------- MFMA flash attention v9: staged hbf + banded loop + fused res+LN ----------------
// Block = 16 query rows of one batch, 8 waves = 8 heads. Static softmax (scores << 1, bias <= 0).
// hbf tile (16x256) staged ONCE per block via global_load_lds with pre-swizzled source
// (linear LDS dest + XOR-swizzled global address; same involution applied on the ds_read).
__global__ __launch_bounds__(512) void attn9_k(const ushort* __restrict__ hbf,
                                               const ushort* __restrict__ qwb,
                                               const float* __restrict__ qscale,
                                               const ushort* __restrict__ Kbf,
                                               const ushort* __restrict__ Vtb,
                                               const float* __restrict__ gamma,
                                               const float* __restrict__ strength_p,
                                               float* __restrict__ h,
                                               const float* __restrict__ lnw,
                                               const float* __restrict__ lnb,
                                               ushort* __restrict__ yb) {
  __shared__ __align__(16) ushort Pl[8][16][88];   // per-wave Q staging / P tile
  __shared__ __align__(16) float hs[16][256];      // time-shared: hbf staging (start) / update slice (end)
  ushort* hsb = (ushort*)&hs[0][0];                // 16x256 bf16 = 8 KB view
  int tid = threadIdx.x;
  int w = tid >> 6, lane = tid & 63;
  int c = lane & 15, g = lane >> 4;
  // XCD swizzle: batch b == XCD id
  int lid = (blockIdx.x & 7) * 64 + (blockIdx.x >> 3);
  int b = lid >> 6;
  int chunk = lid & 63;
  int hh = w;
  int bh = b * HH + hh;
  int q0 = chunk * 16;
  int qg = q0 + c;
  int dtile = chunk >> 2;
  float ss = fmaxf(strength_p[0], 0.f) * exp2f(-(float)hh / 8.0f);
  const float L2E = 1.4426950408889634f;

  // ---- cooperative hbf staging: row = tid>>5, slot = tid&31; source pre-swizzled ----
  {
    int row = tid >> 5, slot = tid & 31;
    async_copy16(&hsb[row * 256 + slot * 8],
                 hbf + ((size_t)(b * DD + q0 + row)) * EE + ((slot ^ (row & 7)) * 8));
  }
  __syncthreads();

  // ---- fused Q projection: Q[16q x 32e] for this wave's head, K=256, A from LDS ----
  f4 qa0 = {0.f, 0.f, 0.f, 0.f}, qa1 = {0.f, 0.f, 0.f, 0.f};
  {
    const ushort* Bb0 = qwb + ((size_t)(hh * HDD + c)) * EE + 8 * g;
    const ushort* Bb1 = Bb0 + (size_t)16 * EE;
    #pragma unroll
    for (int kk = 0; kk < 8; kk++) {
      int kg = kk * 4 + g;
      short8 a  = *(const short8*)&hsb[c * 256 + ((kg ^ (c & 7)) << 3)];
      short8 b0 = *(const short8*)(Bb0 + kk * 32);
      short8 b1 = *(const short8*)(Bb1 + kk * 32);
      qa0 = __builtin_amdgcn_mfma_f32_16x16x32_bf16(a, b0, qa0, 0, 0, 0);
      qa1 = __builtin_amdgcn_mfma_f32_16x16x32_bf16(a, b1, qa1, 0, 0, 0);
    }
  }
  {
    const float4 qsv = *(const float4*)&qscale[b * DD + q0 + 4 * g];
    float qs[4] = {qsv.x, qsv.y, qsv.z, qsv.w};
    #pragma unroll
    for (int r = 0; r < 4; r++) {
      float sc = qs[r] * 0.17677669529663687f;
      Pl[w][4 * g + r][c]      = f2bf(qa0[r] * sc);
      Pl[w][4 * g + r][16 + c] = f2bf(qa1[r] * sc);
    }
  }
  // wave-internal LDS write->read is in-order
  short8 qf = *(const short8*)&Pl[w][c][8 * g];

  // ---- tile band from window cut: keep tiles with relative contribution >= e^-14 ----
  int Wi = (ss > 1e-8f) ? (int)fminf(14.0f / ss, 1.0e6f) : 1000000;
  int hi = min(15, (q0 + 15 + Wi) >> 6);
  int tlo = q0 - 63 - Wi;
  int lo = (tlo <= 0) ? 0 : ((tlo + 63) >> 6);

  f4 oacc0 = {0.f, 0.f, 0.f, 0.f};
  f4 oacc1 = {0.f, 0.f, 0.f, 0.f};
  float lpart = 0.f;

  const ushort* Kb0 = Kbf + (((size_t)bh * DD + c) << 5) + (g << 3);
  const ushort* Vb0 = Vtb + ((size_t)(bh * HDD + c)) * DD + (g << 3);

  // preload K fragments for the first tile
  short8 kf0 = *(const short8*)(Kb0 + (((size_t)(lo * 64 + 0))  << 5));
  short8 kf1 = *(const short8*)(Kb0 + (((size_t)(lo * 64 + 16)) << 5));
  short8 kf2 = *(const short8*)(Kb0 + (((size_t)(lo * 64 + 32)) << 5));
  short8 kf3 = *(const short8*)(Kb0 + (((size_t)(lo * 64 + 48)) << 5));

  for (int ks = lo; ks <= hi; ks++) {
    // early V loads: in flight across the whole softmax chain
    const ushort* vb = Vb0 + ks * 64;
    short8 va0 = *(const short8*)(vb);
    short8 va1 = *(const short8*)(vb + 32);
    short8 vc0 = *(const short8*)(vb + (size_t)16 * DD);
    short8 vc1 = *(const short8*)(vb + (size_t)16 * DD + 32);
    // QK^T (swapped): S^T[k][q]
    f4 z = {0.f, 0.f, 0.f, 0.f};
    f4 sa[4];
    sa[0] = __builtin_amdgcn_mfma_f32_16x16x32_bf16(kf0, qf, z, 0, 0, 0);
    sa[1] = __builtin_amdgcn_mfma_f32_16x16x32_bf16(kf1, qf, z, 0, 0, 0);
    sa[2] = __builtin_amdgcn_mfma_f32_16x16x32_bf16(kf2, qf, z, 0, 0, 0);
    sa[3] = __builtin_amdgcn_mfma_f32_16x16x32_bf16(kf3, qf, z, 0, 0, 0);
    // prefetch next tile's K fragments (hides under softmax VALU)
    if (ks < hi) {
      const ushort* kb = Kb0 + (((size_t)((ks + 1) * 64)) << 5);
      kf0 = *(const short8*)(kb);
      kf1 = *(const short8*)(kb + (16 << 5));
      kf2 = *(const short8*)(kb + (32 << 5));
      kf3 = *(const short8*)(kb + (48 << 5));
    }
    // bias (lane owns query col c; key = ks*64 + t*16 + 4g + r)
    float s[16];
    if (ks == dtile) {
      #pragma unroll
      for (int t = 0; t < 4; t++) {
        #pragma unroll
        for (int r = 0; r < 4; r++) {
          int k = ks * 64 + t * 16 + 4 * g + r;
          float ad = fabsf((float)(qg - k));
          s[t * 4 + r] = (k == qg) ? -1e30f : fmaf(-ss, ad, sa[t][r]);
        }
      }
    } else {
      float sgn = (ks > dtile) ? -ss : ss;   // bias = sgn*(k - qg) <= 0
      int kb2 = ks * 64 + 4 * g - qg;
      #pragma unroll
      for (int t = 0; t < 4; t++) {
        #pragma unroll
        for (int r = 0; r < 4; r++) {
          float dk = (float)(kb2 + t * 16 + r);
          s[t * 4 + r] = fmaf(sgn, dk, sa[t][r]);
        }
      }
    }
    // static-reference exp + partial sum + truncated bf16 pack
    #pragma unroll
    for (int i = 0; i < 16; i++) {
      float p = exp2f(s[i] * L2E);
      s[i] = p;
      lpart += p;
    }
    #pragma unroll
    for (int t = 0; t < 4; t++) {
      uint2 u;
      u.x = __builtin_amdgcn_perm(__float_as_uint(s[t * 4 + 1]), __float_as_uint(s[t * 4 + 0]), 0x07060302u);
      u.y = __builtin_amdgcn_perm(__float_as_uint(s[t * 4 + 3]), __float_as_uint(s[t * 4 + 2]), 0x07060302u);
      *(uint2*)&Pl[w][c][t * 16 + 4 * g] = u;
    }
    // PV: O[q][e] += P[q][k] V[k][e]
    short8 pa0 = *(const short8*)&Pl[w][c][8 * g];
    short8 pa1 = *(const short8*)&Pl[w][c][32 + 8 * g];
    oacc0 = __builtin_amdgcn_mfma_f32_16x16x32_bf16(pa0, va0, oacc0, 0, 0, 0);
    oacc1 = __builtin_amdgcn_mfma_f32_16x16x32_bf16(pa0, vc0, oacc1, 0, 0, 0);
    oacc0 = __builtin_amdgcn_mfma_f32_16x16x32_bf16(pa1, va1, oacc0, 0, 0, 0);
    oacc1 = __builtin_amdgcn_mfma_f32_16x16x32_bf16(pa1, vc1, oacc1, 0, 0, 0);
  }

  // ---- l reduce across the 4 lanes sharing query c ----
  lpart += __shfl_xor(lpart, 16);
  lpart += __shfl_xor(lpart, 32);
  float linv = 1.0f / lpart;

  // ---- all waves done reading hsb (Q-proj) before hs is overwritten ----
  __syncthreads();

  // ---- deposit gamma * O / l into the block's update slice ----
  #pragma unroll
  for (int r = 0; r < 4; r++) {
    float li = __shfl(linv, 4 * g + r);
    int row = 4 * g + r;
    int e0 = hh * HDD + c, e1 = hh * HDD + 16 + c;
    hs[row][e0] = gamma[e0] * oacc0[r] * li;
    hs[row][e1] = gamma[e1] * oacc1[r] * li;
  }
  __syncthreads();

  // ---- fused residual + LayerNorm: wave w handles rows 2w, 2w+1 ----
  #pragma unroll
  for (int rr = 0; rr < 2; rr++) {
    int row = 2 * w + rr;
    size_t base = ((size_t)(b * DD + q0 + row)) * EE + 4 * lane;
    const float4 ho = *(const float4*)&h[base];
    const float4 ha = *(const float4*)&hs[row][4 * lane];
    float4 v;
    v.x = ho.x + ha.x; v.y = ho.y + ha.y; v.z = ho.z + ha.z; v.w = ho.w + ha.w;
    *(float4*)&h[base] = v;
    float s  = v.x + v.y + v.z + v.w;
    float s2 = v.x * v.x + v.y * v.y + v.z * v.z + v.w * v.w;
    #pragma unroll
    for (int off = 32; off; off >>= 1) {
      s  += __shfl_xor(s, off);
      s2 += __shfl_xor(s2, off);
    }
    float mean = s * (1.0f / EE);
    float var = s2 * (1.0f / EE) - mean * mean;
    float rs = rsqrtf(var + 1e-5f);
    const float4 wv = *(const float4*)&lnw[4 * lane];
    const float4 bv = *(const float4*)&lnb[4 * lane];
    ushort4 o;
    o.x = f2bf((v.x - mean) * rs * wv.x + bv.x);
    o.y = f2bf((v.y - mean) * rs * wv.y + bv.y);
    o.z = f2bf((v.z - mean) * rs * wv.z + bv.z);
    o.w = f2bf((v.w - mean) * rs * wv.w + bv.w);
    *(ushort4*)&yb[base] = o;
  }
}

// ---------------- fused tail: LN(h) -> corr GEMM (+bias, exact GELU) -> row-dot w2 -> out ----------------
// 256 blocks x 32 rows, 4 waves. LN during A-staging (fp32 stats, bf16 XOR-swizzled LDS tile);
// corr_w1 B-fragments direct from L2; GELU in fp32 registers; out = per-lane ni-sum + c-butterfly
// + 4-wave LDS reduce.
__global__ __launch_bounds__(256) void tail_k(const float* __restrict__ hin,
                                              const float* __restrict__ lnw,
                                              const float* __restrict__ lnb,
                                              const ushort* __restrict__ cw1b,
                                              const float* __restrict__ b1,
                                              const float* __restrict__ w2,
                                              const float* __restrict__ b2,
                                              float* __restrict__ out) {
  __shared__ __align__(16) ushort Ab[32 * 256];
  __shared__ float red[4][32];
  int tid = threadIdx.x;
  int w = tid >> 6, lane = tid & 63;
  int c = lane & 15, g = lane >> 4;
  int m0 = blockIdx.x * 32;

  // ---- LN staging: wave w rows w*8..w*8+7, one row per iteration ----
  #pragma unroll
  for (int it = 0; it < 8; it++) {
    int row = w * 8 + it;
    const float4 v = *(const float4*)&hin[((size_t)(m0 + row)) * EE + 4 * lane];
    float s  = v.x + v.y + v.z + v.w;
    float s2 = v.x * v.x + v.y * v.y + v.z * v.z + v.w * v.w;
    #pragma unroll
    for (int off = 32; off; off >>= 1) {
      s  += __shfl_xor(s, off);
      s2 += __shfl_xor(s2, off);
    }
    float mean = s * (1.0f / EE);
    float var = s2 * (1.0f / EE) - mean * mean;
    float rs = rsqrtf(var + 1e-5f);
    const float4 wv = *(const float4*)&lnw[4 * lane];
    const float4 bv = *(const float4*)&lnb[4 * lane];
    ushort4 o;
    o.x = f2bf((v.x - mean) * rs * wv.x + bv.x);
    o.y = f2bf((v.y - mean) * rs * wv.y + bv.y);
    o.z = f2bf((v.z - mean) * rs * wv.z + bv.z);
    o.w = f2bf((v.w - mean) * rs * wv.w + bv.w);
    int slot = lane >> 1;
    int slotp = slot ^ (row & 7);
    *(ushort4*)&Ab[row * 256 + slotp * 8 + (lane & 1) * 4] = o;
  }
  __syncthreads();

  // ---- GEMM: C[32 x 256] = LN(h) @ cw1^T; wave w owns cols w*64..w*64+63 ----
  f4 acc[2][4] = {};
  int n0w = w * 64;
  #pragma unroll
  for (int kstep = 0; kstep < 8; kstep++) {
    short8 af[2], bf_[4];
    #pragma unroll
    for (int mi = 0; mi < 2; mi++) {
      int row = mi * 16 + c;
      int slot = (kstep * 4 + g) ^ (row & 7);
      af[mi] = *(const short8*)&Ab[row * 256 + slot * 8];
    }
    #pragma unroll
    for (int ni = 0; ni < 4; ni++) {
      int col = n0w + ni * 16 + c;
      bf_[ni] = *(const short8*)(cw1b + (size_t)col * EE + kstep * 32 + 8 * g);
    }
    #pragma unroll
    for (int mi = 0; mi < 2; mi++)
      #pragma unroll
      for (int ni = 0; ni < 4; ni++)
        acc[mi][ni] = __builtin_amdgcn_mfma_f32_16x16x32_bf16(af[mi], bf_[ni], acc[mi][ni], 0, 0, 0);
  }

  // ---- epilogue: gelu(acc + b1[col]) * w2[col], sum over cols ----
  float b1v[4], w2v[4];
  #pragma unroll
  for (int ni = 0; ni < 4; ni++) {
    int col = n0w + ni * 16 + c;
    b1v[ni] = b1[col];
    w2v[ni] = w2[col];
  }
  #pragma unroll
  for (int mi = 0; mi < 2; mi++) {
    #pragma unroll
    for (int r = 0; r < 4; r++) {
      float s = 0.f;
      #pragma unroll
      for (int ni = 0; ni < 4; ni++) {
        float v = acc[mi][ni][r] + b1v[ni];
        float gl = 0.5f * v * (1.0f + erff(v * 0.70710678118654752f));
        s += gl * w2v[ni];
      }
      // butterfly over the 16 c-lanes
      s += __shfl_xor(s, 1);
      s += __shfl_xor(s, 2);
      s += __shfl_xor(s, 4);
      s += __shfl_xor(s, 8);
      if (c == 0) red[w][mi * 16 + 4 * g + r] = s;
    }
  }
  __syncthreads();
  if (tid < 32) {
    float s = red[0][tid] + red[1][tid] + red[2][tid] + red[3][tid];
    out[m0 + tid] = s + b2[0];
  }
}

extern "C" void kernel_launch(void* const* d_in, const int* in_sizes, int n_in,
                              void* d_out, int out_size, void* d_ws, size_t ws_size,
                              hipStream_t stream) {
  const float* x            = (const float*)d_in[0];
  const float* value_w      = (const float*)d_in[1];
  const float* value_b      = (const float*)d_in[2];
  const float* feature_embed= (const float*)d_in[3];
  const float* binary_w     = (const float*)d_in[4];
  const float* qw           = (const float*)d_in[5];
  const float* kw           = (const float*)d_in[6];
  const float* vw           = (const float*)d_in[7];
  const float* film_alpha   = (const float*)d_in[8];
  const float* film_a       = (const float*)d_in[9];
  const float* ln1_w        = (const float*)d_in[10];
  const float* ln1_b        = (const float*)d_in[11];
  const float* ffn_w1       = (const float*)d_in[12];
  const float* ffn_b1       = (const float*)d_in[13];
  const float* ffn_w2       = (const float*)d_in[14];
  const float* ffn_b2       = (const float*)d_in[15];
  const float* gamma_attn   = (const float*)d_in[16];
  const float* gamma_ffn    = (const float*)d_in[17];
  const float* corr_ln_w    = (const float*)d_in[18];
  const float* corr_ln_b    = (const float*)d_in[19];
  const float* corr_w1      = (const float*)d_in[20];
  const float* corr_b1      = (const float*)d_in[21];
  const float* corr_w2      = (const float*)d_in[22];
  const float* corr_b2      = (const float*)d_in[23];
  const float* alibi_strength=(const float*)d_in[24];

  const size_t ME = (size_t)BD * DD * EE;   // 2M
  float* ws = (float*)d_ws;
  float* qscale = ws;                       // 8192 f
  float* hb     = qscale + BD * DD;         // 2M f
  ushort* kv_bf = (ushort*)(hb + ME);       // 2M us
  ushort* hb_bf = kv_bf + ME;               // 2M us
  ushort* yb_bf = hb_bf + ME;               // 2M us
  ushort* tb_bf = yb_bf + ME;               // 4M us
  ushort* Kbf   = tb_bf + 2 * ME;           // 2M us
  ushort* Vtb   = Kbf + ME;                 // 2M us
  ushort* wbf   = Vtb + ME;                 // 524288 us
  ushort* qwb   = wbf;
  ushort* kwb   = wbf + 65536;              // kw rows 0-255, vw rows 256-511 (contiguous)
  ushort* w1b   = wbf + 196608;
  ushort* w2b   = wbf + 327680;
  ushort* cw1b  = wbf + 458752;

  const int M = BD * DD;   // 8192

  k_pro<<<8192 + 8 + 2048, 256, 0, stream>>>(x, value_w, value_b, feature_embed, binary_w,
                                             kv_bf, hb, hb_bf,
                                             film_alpha, film_a, qscale,
                                             qw, kw, vw, ffn_w1, ffn_w2, corr_w1, wbf);

  // K+V projection fused: N=512 over [kw;vw]
  mgemm_k<0, 256><<<dim3(512 / 64, M / 128), 512, 0, stream>>>(kv_bf, kwb, Kbf, Vtb, 512,
                                                               nullptr, nullptr, nullptr);

  for (int layer = 0; layer < 2; layer++) {
    attn9_k<<<dim3(BD * (DD / 16)), 512, 0, stream>>>(hb_bf, qwb, qscale, Kbf, Vtb,
                                                      gamma_attn, alibi_strength, hb,
                                                      ln1_w, ln1_b, yb_bf);
    mgemm_k<1, 256><<<dim3((2 * EE) / 64, M / 128), 512, 0, stream>>>(yb_bf, w1b, tb_bf, nullptr,
                                                                      2 * EE, ffn_b1, nullptr, nullptr);
    mgemm_k<2, 512><<<dim3(EE / 64, M / 128), 512, 0, stream>>>(tb_bf, w2b, hb_bf, nullptr,
                                                                EE, ffn_b2, gamma_ffn, hb);
  }

  tail_k<<<M / 32, 256, 0, stream>>>(hb, corr_ln_w, corr_ln_b, cw1b,
                                     corr_b1, corr_w2, corr_b2, (float*)d_out);
}